// Round 1
// baseline (1844.020 us; speedup 1.0000x reference)
//
#include <hip/hip_runtime.h>
#include <math.h>

// Problem constants
static constexpr int H = 256, L = 141, N1 = 9, N2 = 34, N3 = 98;
static constexpr int B = 64, S = 512;

// ---------------------------------------------------------------------------
// Tiled fp32 GEMM: C = epi(A @ opB(B)).  64x64 block tile, K-chunk 16,
// 256 threads, 4x4 micro-tile per thread (VALU-bound: 2 ds_read_b128 per 16 FMA).
// Requires K % 16 == 0 (true for all uses: 768/256/512/36096; ksplit chunk 1504).
// EPI: 0 = plain store, 1 = tanh(acc + aux[n]), 2 = acc + pad-mask(n), 3 = atomicAdd
// TRANSB: B stored (N x K) row-major, logical B^T used.
// BVEC: vectorized float4 staging for B (needs ldb%4==0 and N%64==0).
// KSPLIT: grid.z splits K (kChunk per block) instead of batching.
// ---------------------------------------------------------------------------
template<int EPI, bool TRANSB, bool BVEC, bool KSPLIT>
__global__ __launch_bounds__(256) void gemm64(
    const float* __restrict__ A, int lda, long strA,
    const float* __restrict__ Bm, int ldb, long strB,
    float* __restrict__ C, int ldc, long strC,
    int M, int N, int K,
    const float* __restrict__ aux, const int* __restrict__ mask, int maskStride,
    int kChunk)
{
    __shared__ float As[16][64];   // As[k][m]
    __shared__ float Bs[16][64];   // Bs[k][n]
    const int tid = threadIdx.x;
    const int bz  = blockIdx.z;
    long aOff, bOff, cOff;
    int kBeg, kEnd;
    if (KSPLIT) {
        aOff = bOff = cOff = 0;
        kBeg = bz * kChunk;
        kEnd = kBeg + kChunk; if (kEnd > K) kEnd = K;
    } else {
        aOff = (long)bz * strA; bOff = (long)bz * strB; cOff = (long)bz * strC;
        kBeg = 0; kEnd = K;
    }
    const int m0 = blockIdx.y * 64, n0 = blockIdx.x * 64;
    const int ty = tid >> 4, tx = tid & 15;
    const int am = tid >> 2, akq = tid & 3;   // staging: row, k-quad
    float acc[4][4] = {};

    for (int kk = kBeg; kk < kEnd; kk += 16) {
        // ---- stage A (transposed into LDS), float4 along k ----
        {
            float4 v = make_float4(0.f, 0.f, 0.f, 0.f);
            int m = m0 + am;
            if (m < M) v = *(const float4*)(A + aOff + (long)m * lda + (kk + akq * 4));
            As[akq*4+0][am] = v.x; As[akq*4+1][am] = v.y;
            As[akq*4+2][am] = v.z; As[akq*4+3][am] = v.w;
        }
        // ---- stage B ----
        if (!TRANSB) {
            if (BVEC) {
                int k = tid >> 4, n = (tid & 15) << 2;
                float4 v = *(const float4*)(Bm + bOff + (long)(kk + k) * ldb + (n0 + n));
                *(float4*)&Bs[k][n] = v;
            } else {
                #pragma unroll
                for (int i = 0; i < 4; i++) {
                    int idx = tid + i * 256;
                    int k = idx >> 6, n = idx & 63;
                    float v = 0.f;
                    if (n0 + n < N) v = Bm[bOff + (long)(kk + k) * ldb + (n0 + n)];
                    Bs[k][n] = v;
                }
            }
        } else {
            float4 v = make_float4(0.f, 0.f, 0.f, 0.f);
            int n = n0 + am;
            if (n < N) v = *(const float4*)(Bm + bOff + (long)n * ldb + (kk + akq * 4));
            Bs[akq*4+0][am] = v.x; Bs[akq*4+1][am] = v.y;
            Bs[akq*4+2][am] = v.z; Bs[akq*4+3][am] = v.w;
        }
        __syncthreads();
        // ---- compute ----
        #pragma unroll
        for (int k = 0; k < 16; k++) {
            float4 a4 = *(const float4*)&As[k][ty << 2];
            float4 b4 = *(const float4*)&Bs[k][tx << 2];
            float av[4] = {a4.x, a4.y, a4.z, a4.w};
            float bv[4] = {b4.x, b4.y, b4.z, b4.w};
            #pragma unroll
            for (int i = 0; i < 4; i++)
                #pragma unroll
                for (int j = 0; j < 4; j++)
                    acc[i][j] += av[i] * bv[j];
        }
        __syncthreads();
    }
    // ---- epilogue ----
    #pragma unroll
    for (int i = 0; i < 4; i++) {
        int m = m0 + (ty << 2) + i;
        if (m >= M) continue;
        #pragma unroll
        for (int j = 0; j < 4; j++) {
            int n = n0 + (tx << 2) + j;
            if (n >= N) continue;
            float v = acc[i][j];
            if (EPI == 1) v = tanhf(v + aux[n]);
            if (EPI == 2) {
                int tok = mask[(long)bz * maskStride + n];
                if (tok == 0 || tok == 101 || tok == 102) v -= 1e30f;
            }
            if (EPI == 3) atomicAdd(C + cOff + (long)m * ldc + n, v);
            else          C[cOff + (long)m * ldc + n] = v;
        }
    }
}

// ---------------------------------------------------------------------------
// Naive small matmul for the tiny label-path ops (M<=141, K<=768).
// C[m][n] = act( bias[n] + sum_k A[m*sAm+k*sAk]*B[k*sBk+n]
//                        + sum_k2 A2[...]*B2[...] ) * (mulsrc? mulsrc[m][n]:1)
// act: 0 none, 1 relu, 2 sigmoid.  N==256 always, C compact MxN.
// ---------------------------------------------------------------------------
__global__ __launch_bounds__(256) void small_mm(
    const float* __restrict__ A, int sAm, int sAk,
    const float* __restrict__ Bp, int sBk,
    const float* __restrict__ A2, int sA2m, int sA2k,
    const float* __restrict__ B2, int sB2k,
    const float* __restrict__ bias,
    const float* __restrict__ mulsrc,
    float* __restrict__ C,
    int N, int K, int K2, int act)
{
    int m = blockIdx.y;
    int n = blockIdx.x * 256 + threadIdx.x;
    if (n >= N) return;
    float acc = bias ? bias[n] : 0.f;
    for (int k = 0; k < K; k++)
        acc += A[(long)m * sAm + (long)k * sAk] * Bp[(long)k * sBk + n];
    if (A2)
        for (int k = 0; k < K2; k++)
            acc += A2[(long)m * sA2m + (long)k * sA2k] * B2[(long)k * sB2k + n];
    if (act == 1) acc = fmaxf(acc, 0.f);
    else if (act == 2) acc = 1.f / (1.f + __expf(-acc));
    if (mulsrc) acc *= mulsrc[(long)m * N + n];
    C[(long)m * N + n] = acc;
}

// ---------------------------------------------------------------------------
// Fused LSTM-gates: per row m, thread n computes gates i,o,u(,f) =
// X[m]@W + b (+ Xu[m]@U), then c/h elementwise.
// mode 0: c = i*u;  mode 1: c = i*u + sig(gf)*cmod;  mode 2: c = i*u + cmod
// ---------------------------------------------------------------------------
__global__ __launch_bounds__(256) void lstm_gates(
    const float* __restrict__ X, const float* __restrict__ Xu,
    const float* __restrict__ Wi, const float* __restrict__ bi,
    const float* __restrict__ Wo, const float* __restrict__ bo,
    const float* __restrict__ Wu, const float* __restrict__ bu,
    const float* __restrict__ Wf, const float* __restrict__ bf,
    const float* __restrict__ Ui, const float* __restrict__ Uo,
    const float* __restrict__ Uu, const float* __restrict__ Uf,
    const float* __restrict__ cmod,
    float* __restrict__ h, float* __restrict__ c, int mode)
{
    __shared__ float xs[256], xus[256];
    int m = blockIdx.x, n = threadIdx.x;
    xs[n] = X[m * 256 + n];
    if (Xu) xus[n] = Xu[m * 256 + n];
    __syncthreads();
    float gi = bi[n], go = bo[n], gu = bu[n];
    float gf = Wf ? bf[n] : 0.f;
    for (int k = 0; k < 256; k++) {
        float x = xs[k];
        gi += x * Wi[k * 256 + n];
        go += x * Wo[k * 256 + n];
        gu += x * Wu[k * 256 + n];
        if (Wf) gf += x * Wf[k * 256 + n];
    }
    if (Ui) {
        for (int k = 0; k < 256; k++) {
            float x = xus[k];
            gi += x * Ui[k * 256 + n];
            go += x * Uo[k * 256 + n];
            gu += x * Uu[k * 256 + n];
            if (Uf) gf += x * Uf[k * 256 + n];
        }
    }
    float iv = 1.f / (1.f + __expf(-gi));
    float ov = 1.f / (1.f + __expf(-go));
    float uv = tanhf(gu);
    float cv = iv * uv;
    if (mode == 1)      cv += (1.f / (1.f + __expf(-gf))) * cmod[m * 256 + n];
    else if (mode == 2) cv += cmod[m * 256 + n];
    h[m * 256 + n] = ov * tanhf(cv);
    c[m * 256 + n] = cv;
}

// Build le_cat (141 x 768) = [h1x | h2x | temp]
__global__ __launch_bounds__(256) void build_lecat(
    const float* __restrict__ h11, const float* __restrict__ h12,
    const float* __restrict__ h21, const float* __restrict__ h22,
    const float* __restrict__ h31, const float* __restrict__ h32,
    const float* __restrict__ tmpP, float* __restrict__ lecat)
{
    int l = blockIdx.x;
    const float *pa, *pb; int r;
    if (l < N1)            { pa = h11; pb = h12; r = l; }
    else if (l < N1 + N2)  { pa = h21; pb = h22; r = l - N1; }
    else                   { pa = h31; pb = h32; r = l - N1 - N2; }
    for (int j = threadIdx.x; j < 768; j += 256) {
        float v;
        if (j < 256)      v = pa[r * 256 + j];
        else if (j < 512) v = pb[r * 256 + (j - 256)];
        else              v = tmpP[l * 256 + (j - 512)];
        lecat[(long)l * 768 + j] = v;
    }
}

// Row softmax over S=512, in place. One block per (b,l) row.
__global__ __launch_bounds__(256) void softmax512(float* __restrict__ att)
{
    __shared__ float red[256];
    float* row = att + (long)blockIdx.x * 512;
    int t = threadIdx.x;
    float a = row[t], b = row[t + 256];
    red[t] = fmaxf(a, b);
    __syncthreads();
    for (int s = 128; s > 0; s >>= 1) {
        if (t < s) red[t] = fmaxf(red[t], red[t + s]);
        __syncthreads();
    }
    float m = red[0];
    __syncthreads();
    float ea = __expf(a - m), eb = __expf(b - m);
    red[t] = ea + eb;
    __syncthreads();
    for (int s = 128; s > 0; s >>= 1) {
        if (t < s) red[t] += red[t + s];
        __syncthreads();
    }
    float inv = 1.f / red[0];
    row[t] = ea * inv;
    row[t + 256] = eb * inv;
}

__global__ __launch_bounds__(256) void zero_kernel(float* __restrict__ p, int n)
{
    int i = blockIdx.x * 256 + threadIdx.x;
    if (i < n) p[i] = 0.f;
}

__global__ __launch_bounds__(256) void out_final(
    const float* __restrict__ acc, const float* __restrict__ ob,
    float* __restrict__ out, int total)
{
    int i = blockIdx.x * 256 + threadIdx.x;
    if (i < total) {
        float v = acc[i] + ob[i % L];
        out[i] = 1.f / (1.f + __expf(-v));
    }
}

extern "C" void kernel_launch(void* const* d_in, const int* in_sizes, int n_in,
                              void* d_out, int out_size, void* d_ws, size_t ws_size,
                              hipStream_t stream)
{
    (void)in_sizes; (void)n_in; (void)out_size; (void)ws_size;
    const int*   inputs      = (const int*)d_in[0];
    const float* text_hidden = (const float*)d_in[1];
    const float* label_enc   = (const float*)d_in[2];
    const float* w12   = (const float*)d_in[3];
    const float* w23   = (const float*)d_in[4];
    const float* fre12 = (const float*)d_in[5];
    const float* fre23 = (const float*)d_in[6];
    const float* wi1_W = (const float*)d_in[7],  *wi1_b = (const float*)d_in[8];
    const float* wf1_W = (const float*)d_in[9],  *wf1_b = (const float*)d_in[10];
    const float* wo1_W = (const float*)d_in[11], *wo1_b = (const float*)d_in[12];
    const float* wu1_W = (const float*)d_in[13], *wu1_b = (const float*)d_in[14];
    const float* wi2_W = (const float*)d_in[15], *wi2_b = (const float*)d_in[16];
    const float* wf2_W = (const float*)d_in[17], *wf2_b = (const float*)d_in[18];
    const float* wo2_W = (const float*)d_in[19], *wo2_b = (const float*)d_in[20];
    const float* wu2_W = (const float*)d_in[21], *wu2_b = (const float*)d_in[22];
    const float* ui1_W = (const float*)d_in[23], *uf1_W = (const float*)d_in[24];
    const float* uo1_W = (const float*)d_in[25], *uu1_W = (const float*)d_in[26];
    const float* ui2_W = (const float*)d_in[27], *uf2_W = (const float*)d_in[28];
    const float* uo2_W = (const float*)d_in[29], *uu2_W = (const float*)d_in[30];
    const float* mix_W = (const float*)d_in[31], *mix_b = (const float*)d_in[32];
    const float* tt_W  = (const float*)d_in[33], *tt_b  = (const float*)d_in[34];
    const float* Amat  = (const float*)d_in[35], *Wp    = (const float*)d_in[36];
    const float* out_W = (const float*)d_in[37], *out_b = (const float*)d_in[38];
    float* out = (float*)d_out;

    const float* v1 = label_enc;
    const float* v2 = label_enc + N1 * H;
    const float* v3 = label_enc + (N1 + N2) * H;

    // ---- workspace bump allocator (all sizes multiple of 4 floats) ----
    float* ws = (float*)d_ws;
    float* text   = ws; ws += (long)B * S * H;      // 8,388,608
    float* att    = ws; ws += (long)B * L * S;      // 4,620,288
    float* feat   = ws; ws += (long)B * L * H;      // 2,310,144
    float* le     = ws; ws += L * H;
    float* AL     = ws; ws += L * H;
    float* tmpP   = ws; ws += L * H;
    float* lecat  = ws; ws += L * 768;
    float* h11  = ws; ws += N1 * H;   float* c11  = ws; ws += N1 * H;
    float* h21  = ws; ws += N2 * H;   float* c21  = ws; ws += N2 * H;
    float* h21t = ws; ws += N2 * H;   float* c21p = ws; ws += N2 * H;
    float* h31  = ws; ws += N3 * H;   float* c31  = ws; ws += N3 * H;
    float* h31t = ws; ws += N3 * H;   float* c31p = ws; ws += N3 * H;
    float* h32  = ws; ws += N3 * H;   float* c32  = ws; ws += N3 * H;
    float* h22  = ws; ws += N2 * H;   float* c22  = ws; ws += N2 * H;
    float* h22t = ws; ws += N2 * H;   float* wv2  = ws; ws += N3 * H;
    float* fcb  = ws; ws += N3 * H;   float* add22= ws; ws += N2 * H;
    float* h12  = ws; ws += N1 * H;   float* c12s = ws; ws += N1 * H;
    float* h12t = ws; ws += N1 * H;   float* wv1  = ws; ws += N2 * H;
    float* fc2b = ws; ws += N2 * H;   float* add12= ws; ws += N1 * H;
    float* outacc = ws; ws += B * L;

    // ---- 1. text = tanh(text_hidden @ tt_W + tt_b)  (M=32768,N=256,K=768) ----
    gemm64<1, false, true, false><<<dim3(H / 64, (B * S) / 64, 1), 256, 0, stream>>>(
        text_hidden, 768, 0, tt_W, H, 0, text, H, 0,
        B * S, H, 768, tt_b, nullptr, 0, 0);

    // ---- 2. label path ----
    // S1: h11,c11 from v1 (gates i,o,u; W1 set)
    lstm_gates<<<N1, 256, 0, stream>>>(v1, nullptr,
        wi1_W, wi1_b, wo1_W, wo1_b, wu1_W, wu1_b, nullptr, nullptr,
        nullptr, nullptr, nullptr, nullptr, nullptr, h11, c11, 0);
    // S2: h21t = w12^T @ h11 ; c21p = w12^T @ c11 ; gates
    small_mm<<<dim3(1, N2), 256, 0, stream>>>(w12, 1, N2, h11, H,
        nullptr, 0, 0, nullptr, 0, nullptr, nullptr, h21t, H, N1, 0, 0);
    small_mm<<<dim3(1, N2), 256, 0, stream>>>(w12, 1, N2, c11, H,
        nullptr, 0, 0, nullptr, 0, nullptr, nullptr, c21p, H, N1, 0, 0);
    lstm_gates<<<N2, 256, 0, stream>>>(v2, h21t,
        wi1_W, wi1_b, wo1_W, wo1_b, wu1_W, wu1_b, wf1_W, wf1_b,
        ui1_W, uo1_W, uu1_W, uf1_W, c21p, h21, c21, 1);
    // S3
    small_mm<<<dim3(1, N3), 256, 0, stream>>>(w23, 1, N3, h21, H,
        nullptr, 0, 0, nullptr, 0, nullptr, nullptr, h31t, H, N2, 0, 0);
    small_mm<<<dim3(1, N3), 256, 0, stream>>>(w23, 1, N3, c21, H,
        nullptr, 0, 0, nullptr, 0, nullptr, nullptr, c31p, H, N2, 0, 0);
    lstm_gates<<<N3, 256, 0, stream>>>(v3, h31t,
        wi1_W, wi1_b, wo1_W, wo1_b, wu1_W, wu1_b, wf1_W, wf1_b,
        ui1_W, uo1_W, uu1_W, uf1_W, c31p, h31, c31, 1);
    // S4: h32,c32 from v3 (W2 set, no U, no f)
    lstm_gates<<<N3, 256, 0, stream>>>(v3, nullptr,
        wi2_W, wi2_b, wo2_W, wo2_b, wu2_W, wu2_b, nullptr, nullptr,
        nullptr, nullptr, nullptr, nullptr, nullptr, h32, c32, 0);
    // S5
    small_mm<<<dim3(1, N2), 256, 0, stream>>>(fre23, N3, 1, h32, H,
        nullptr, 0, 0, nullptr, 0, nullptr, nullptr, h22t, H, N3, 0, 0);
    small_mm<<<dim3(1, N3), 256, 0, stream>>>(w23, 1, N3, v2, H,
        nullptr, 0, 0, nullptr, 0, nullptr, nullptr, wv2, H, N2, 0, 0);
    // fcb = sig(wv2@wf2_W + h32@uf2_W + wf2_b) * c32
    small_mm<<<dim3(1, N3), 256, 0, stream>>>(wv2, H, 1, wf2_W, H,
        h32, H, 1, uf2_W, H, wf2_b, c32, fcb, H, H, H, 2);
    small_mm<<<dim3(1, N2), 256, 0, stream>>>(w23, N3, 1, fcb, H,
        nullptr, 0, 0, nullptr, 0, nullptr, nullptr, add22, H, N3, 0, 0);
    lstm_gates<<<N2, 256, 0, stream>>>(v2, h22t,
        wi2_W, wi2_b, wo2_W, wo2_b, wu2_W, wu2_b, nullptr, nullptr,
        ui2_W, uo2_W, uu2_W, nullptr, add22, h22, c22, 2);
    // S6
    small_mm<<<dim3(1, N1), 256, 0, stream>>>(fre12, N2, 1, h22, H,
        nullptr, 0, 0, nullptr, 0, nullptr, nullptr, h12t, H, N2, 0, 0);
    small_mm<<<dim3(1, N2), 256, 0, stream>>>(w12, 1, N2, v1, H,
        nullptr, 0, 0, nullptr, 0, nullptr, nullptr, wv1, H, N1, 0, 0);
    small_mm<<<dim3(1, N2), 256, 0, stream>>>(wv1, H, 1, wf2_W, H,
        h22, H, 1, uf2_W, H, wf2_b, c22, fc2b, H, H, H, 2);
    small_mm<<<dim3(1, N1), 256, 0, stream>>>(w12, N2, 1, fc2b, H,
        nullptr, 0, 0, nullptr, 0, nullptr, nullptr, add12, H, N2, 0, 0);
    lstm_gates<<<N1, 256, 0, stream>>>(v1, h12t,
        wi2_W, wi2_b, wo2_W, wo2_b, wu2_W, wu2_b, nullptr, nullptr,
        ui2_W, uo2_W, uu2_W, nullptr, add12, h12, c12s, 2);
    // S7: temp = relu(A @ label_enc @ Wp); le = [h|temp] @ mix_W + mix_b
    small_mm<<<dim3(1, L), 256, 0, stream>>>(Amat, L, 1, label_enc, H,
        nullptr, 0, 0, nullptr, 0, nullptr, nullptr, AL, H, L, 0, 0);
    small_mm<<<dim3(1, L), 256, 0, stream>>>(AL, H, 1, Wp, H,
        nullptr, 0, 0, nullptr, 0, nullptr, nullptr, tmpP, H, H, 0, 1);
    build_lecat<<<L, 256, 0, stream>>>(h11, h12, h21, h22, h31, h32, tmpP, lecat);
    small_mm<<<dim3(1, L), 256, 0, stream>>>(lecat, 768, 1, mix_W, H,
        nullptr, 0, 0, nullptr, 0, mix_b, nullptr, le, H, 768, 0, 0);

    // ---- 3. logits: att[b,l,s] = le @ text[b]^T + pad  (batched over b) ----
    gemm64<2, true, true, false><<<dim3(S / 64, (L + 63) / 64, B), 256, 0, stream>>>(
        le, H, 0, text, H, (long)S * H, att, S, (long)L * S,
        L, S, H, nullptr, inputs, S, 0);

    // ---- 4. softmax over s ----
    softmax512<<<B * L, 256, 0, stream>>>(att);

    // ---- 5. feat[b,l,:] = att[b] @ text[b]  (batched) ----
    gemm64<0, false, true, false><<<dim3(H / 64, (L + 63) / 64, B), 256, 0, stream>>>(
        att, S, (long)L * S, text, H, (long)S * H, feat, H, (long)L * H,
        L, H, S, nullptr, nullptr, 0, 0);

    // ---- 6. out = sig(feat(64x36096) @ out_W + out_b): K-split + atomics ----
    zero_kernel<<<(B * L + 255) / 256, 256, 0, stream>>>(outacc, B * L);
    gemm64<3, false, false, true><<<dim3((L + 63) / 64, 1, 24), 256, 0, stream>>>(
        feat, L * H, 0, out_W, L, 0, outacc, L, 0,
        B, L, L * H, nullptr, nullptr, 0, 1504);
    out_final<<<(B * L + 255) / 256, 256, 0, stream>>>(outacc, out_b, out, B * L);
}

// Round 2
// 978.498 us; speedup vs baseline: 1.8845x; 1.8845x over previous
//
#include <hip/hip_runtime.h>
#include <math.h>

// Problem constants
static constexpr int H = 256, L = 141, N1 = 9, N2 = 34, N3 = 98;
static constexpr int B = 64, S = 512;

// ---------------------------------------------------------------------------
// Tiled fp32 GEMM: C = epi(A @ opB(B)).  64x64 block tile, K-chunk 16,
// 256 threads, 4x4 micro-tile per thread.
// EPI: 0 = plain store, 1 = tanh(acc + aux[n]), 2 = acc + pad-mask(n), 3 = atomicAdd
// TRANSB: B stored (N x K) row-major, logical B^T used.
// BVEC: vectorized float4 staging for B (needs ldb%4==0 and N%64==0).
// KSPLIT: grid.z splits K (kChunk per block) instead of batching.
// ---------------------------------------------------------------------------
template<int EPI, bool TRANSB, bool BVEC, bool KSPLIT>
__global__ __launch_bounds__(256) void gemm64(
    const float* __restrict__ A, int lda, long strA,
    const float* __restrict__ Bm, int ldb, long strB,
    float* __restrict__ C, int ldc, long strC,
    int M, int N, int K,
    const float* __restrict__ aux, const int* __restrict__ mask, int maskStride,
    int kChunk)
{
    __shared__ float As[16][64];   // As[k][m]
    __shared__ float Bs[16][64];   // Bs[k][n]
    const int tid = threadIdx.x;
    const int bz  = blockIdx.z;
    long aOff, bOff, cOff;
    int kBeg, kEnd;
    if (KSPLIT) {
        aOff = bOff = cOff = 0;
        kBeg = bz * kChunk;
        kEnd = kBeg + kChunk; if (kEnd > K) kEnd = K;
    } else {
        aOff = (long)bz * strA; bOff = (long)bz * strB; cOff = (long)bz * strC;
        kBeg = 0; kEnd = K;
    }
    const int m0 = blockIdx.y * 64, n0 = blockIdx.x * 64;
    const int ty = tid >> 4, tx = tid & 15;
    const int am = tid >> 2, akq = tid & 3;   // staging: row, k-quad
    float acc[4][4] = {};

    for (int kk = kBeg; kk < kEnd; kk += 16) {
        // ---- stage A (transposed into LDS), float4 along k ----
        {
            float4 v = make_float4(0.f, 0.f, 0.f, 0.f);
            int m = m0 + am;
            if (m < M) v = *(const float4*)(A + aOff + (long)m * lda + (kk + akq * 4));
            As[akq*4+0][am] = v.x; As[akq*4+1][am] = v.y;
            As[akq*4+2][am] = v.z; As[akq*4+3][am] = v.w;
        }
        // ---- stage B ----
        if (!TRANSB) {
            if (BVEC) {
                int k = tid >> 4, n = (tid & 15) << 2;
                float4 v = *(const float4*)(Bm + bOff + (long)(kk + k) * ldb + (n0 + n));
                *(float4*)&Bs[k][n] = v;
            } else {
                #pragma unroll
                for (int i = 0; i < 4; i++) {
                    int idx = tid + i * 256;
                    int k = idx >> 6, n = idx & 63;
                    float v = 0.f;
                    if (n0 + n < N) v = Bm[bOff + (long)(kk + k) * ldb + (n0 + n)];
                    Bs[k][n] = v;
                }
            }
        } else {
            float4 v = make_float4(0.f, 0.f, 0.f, 0.f);
            int n = n0 + am;
            if (n < N) v = *(const float4*)(Bm + bOff + (long)n * ldb + (kk + akq * 4));
            Bs[akq*4+0][am] = v.x; Bs[akq*4+1][am] = v.y;
            Bs[akq*4+2][am] = v.z; Bs[akq*4+3][am] = v.w;
        }
        __syncthreads();
        // ---- compute ----
        #pragma unroll
        for (int k = 0; k < 16; k++) {
            float4 a4 = *(const float4*)&As[k][ty << 2];
            float4 b4 = *(const float4*)&Bs[k][tx << 2];
            float av[4] = {a4.x, a4.y, a4.z, a4.w};
            float bv[4] = {b4.x, b4.y, b4.z, b4.w};
            #pragma unroll
            for (int i = 0; i < 4; i++)
                #pragma unroll
                for (int j = 0; j < 4; j++)
                    acc[i][j] += av[i] * bv[j];
        }
        __syncthreads();
    }
    // ---- epilogue ----
    #pragma unroll
    for (int i = 0; i < 4; i++) {
        int m = m0 + (ty << 2) + i;
        if (m >= M) continue;
        #pragma unroll
        for (int j = 0; j < 4; j++) {
            int n = n0 + (tx << 2) + j;
            if (n >= N) continue;
            float v = acc[i][j];
            if (EPI == 1) v = tanhf(v + aux[n]);
            if (EPI == 2) {
                int tok = mask[(long)bz * maskStride + n];
                if (tok == 0 || tok == 101 || tok == 102) v -= 1e30f;
            }
            if (EPI == 3) atomicAdd(C + cOff + (long)m * ldc + n, v);
            else          C[cOff + (long)m * ldc + n] = v;
        }
    }
}

// ---------------------------------------------------------------------------
// Latency-optimized small matmul.  C[m][n] = act(bias[n] + A[m,:]@B[:,n]
//   (+ A2[m,:]@B2[:,n])) * (mulsrc? mulsrc[m][n] : 1)
// grid = (N/64, M), block = 256 = 64 n-lanes x 4 k-slices.
// A row staged in LDS; each k-slice runs interleaved k (stride 4) with
// unroll-4 independent accumulators (4 loads in flight / thread); LDS
// reduction across slices.  N == 256 in all uses, K <= 768, K2 <= 256.
// act: 0 none, 1 relu, 2 sigmoid.
// ---------------------------------------------------------------------------
__global__ __launch_bounds__(256) void small_mm(
    const float* __restrict__ A, int sAm, int sAk,
    const float* __restrict__ Bp, int sBk,
    const float* __restrict__ A2, int sA2m, int sA2k,
    const float* __restrict__ B2, int sB2k,
    const float* __restrict__ bias,
    const float* __restrict__ mulsrc,
    float* __restrict__ C,
    int N, int K, int K2, int act)
{
    __shared__ float As[768];
    __shared__ float As2[256];
    __shared__ float red[256];
    const int tid = threadIdx.x;
    const int m = blockIdx.y;
    const int nl = tid & 63, ks = tid >> 6;
    const int n = blockIdx.x * 64 + nl;

    for (int k = tid; k < K; k += 256)
        As[k] = A[(long)m * sAm + (long)k * sAk];
    if (A2)
        for (int k = tid; k < K2; k += 256)
            As2[k] = A2[(long)m * sA2m + (long)k * sA2k];
    __syncthreads();

    float a0 = 0.f, a1 = 0.f, a2 = 0.f, a3 = 0.f;
    {
        int k = ks;
        for (; k + 12 < K; k += 16) {
            float b0 = Bp[(long)(k     ) * sBk + n];
            float b1 = Bp[(long)(k +  4) * sBk + n];
            float b2 = Bp[(long)(k +  8) * sBk + n];
            float b3 = Bp[(long)(k + 12) * sBk + n];
            a0 += As[k] * b0;  a1 += As[k + 4] * b1;
            a2 += As[k + 8] * b2;  a3 += As[k + 12] * b3;
        }
        for (; k < K; k += 4)
            a0 += As[k] * Bp[(long)k * sBk + n];
    }
    if (A2) {
        int k = ks;
        for (; k + 12 < K2; k += 16) {
            float b0 = B2[(long)(k     ) * sB2k + n];
            float b1 = B2[(long)(k +  4) * sB2k + n];
            float b2 = B2[(long)(k +  8) * sB2k + n];
            float b3 = B2[(long)(k + 12) * sB2k + n];
            a0 += As2[k] * b0;  a1 += As2[k + 4] * b1;
            a2 += As2[k + 8] * b2;  a3 += As2[k + 12] * b3;
        }
        for (; k < K2; k += 4)
            a0 += As2[k] * B2[(long)k * sB2k + n];
    }
    red[tid] = a0 + a1 + a2 + a3;
    __syncthreads();
    if (ks == 0 && n < N) {
        float acc = red[nl] + red[64 + nl] + red[128 + nl] + red[192 + nl];
        if (bias) acc += bias[n];
        if (act == 1) acc = fmaxf(acc, 0.f);
        else if (act == 2) acc = 1.f / (1.f + __expf(-acc));
        if (mulsrc) acc *= mulsrc[(long)m * N + n];
        C[(long)m * N + n] = acc;
    }
}

// ---------------------------------------------------------------------------
// Fused LSTM-gates, unroll-4 (16 independent loads in flight per round).
// mode 0: c = i*u;  mode 1: c = i*u + sig(gf)*cmod;  mode 2: c = i*u + cmod
// ---------------------------------------------------------------------------
__global__ __launch_bounds__(256) void lstm_gates(
    const float* __restrict__ X, const float* __restrict__ Xu,
    const float* __restrict__ Wi, const float* __restrict__ bi,
    const float* __restrict__ Wo, const float* __restrict__ bo,
    const float* __restrict__ Wu, const float* __restrict__ bu,
    const float* __restrict__ Wf, const float* __restrict__ bf,
    const float* __restrict__ Ui, const float* __restrict__ Uo,
    const float* __restrict__ Uu, const float* __restrict__ Uf,
    const float* __restrict__ cmod,
    float* __restrict__ h, float* __restrict__ c, int mode)
{
    __shared__ float xs[256], xus[256];
    int m = blockIdx.x, n = threadIdx.x;
    xs[n] = X[m * 256 + n];
    if (Xu) xus[n] = Xu[m * 256 + n];
    __syncthreads();
    float gi = bi[n], go = bo[n], gu = bu[n];
    float gf = Wf ? bf[n] : 0.f;
    for (int k = 0; k < 256; k += 4) {
        float x0 = xs[k], x1 = xs[k+1], x2 = xs[k+2], x3 = xs[k+3];
        long o = (long)k * 256 + n;
        float i0 = Wi[o], i1 = Wi[o+256], i2 = Wi[o+512], i3 = Wi[o+768];
        float q0 = Wo[o], q1 = Wo[o+256], q2 = Wo[o+512], q3 = Wo[o+768];
        float u0 = Wu[o], u1 = Wu[o+256], u2 = Wu[o+512], u3 = Wu[o+768];
        gi += x0*i0 + x1*i1 + x2*i2 + x3*i3;
        go += x0*q0 + x1*q1 + x2*q2 + x3*q3;
        gu += x0*u0 + x1*u1 + x2*u2 + x3*u3;
        if (Wf) {
            float f0 = Wf[o], f1 = Wf[o+256], f2 = Wf[o+512], f3 = Wf[o+768];
            gf += x0*f0 + x1*f1 + x2*f2 + x3*f3;
        }
    }
    if (Ui) {
        for (int k = 0; k < 256; k += 4) {
            float x0 = xus[k], x1 = xus[k+1], x2 = xus[k+2], x3 = xus[k+3];
            long o = (long)k * 256 + n;
            float i0 = Ui[o], i1 = Ui[o+256], i2 = Ui[o+512], i3 = Ui[o+768];
            float q0 = Uo[o], q1 = Uo[o+256], q2 = Uo[o+512], q3 = Uo[o+768];
            float u0 = Uu[o], u1 = Uu[o+256], u2 = Uu[o+512], u3 = Uu[o+768];
            gi += x0*i0 + x1*i1 + x2*i2 + x3*i3;
            go += x0*q0 + x1*q1 + x2*q2 + x3*q3;
            gu += x0*u0 + x1*u1 + x2*u2 + x3*u3;
            if (Uf) {
                float f0 = Uf[o], f1 = Uf[o+256], f2 = Uf[o+512], f3 = Uf[o+768];
                gf += x0*f0 + x1*f1 + x2*f2 + x3*f3;
            }
        }
    }
    float iv = 1.f / (1.f + __expf(-gi));
    float ov = 1.f / (1.f + __expf(-go));
    float uv = tanhf(gu);
    float cv = iv * uv;
    if (mode == 1)      cv += (1.f / (1.f + __expf(-gf))) * cmod[m * 256 + n];
    else if (mode == 2) cv += cmod[m * 256 + n];
    h[m * 256 + n] = ov * tanhf(cv);
    c[m * 256 + n] = cv;
}

// Build le_cat (141 x 768) = [h1x | h2x | temp]
__global__ __launch_bounds__(256) void build_lecat(
    const float* __restrict__ h11, const float* __restrict__ h12,
    const float* __restrict__ h21, const float* __restrict__ h22,
    const float* __restrict__ h31, const float* __restrict__ h32,
    const float* __restrict__ tmpP, float* __restrict__ lecat)
{
    int l = blockIdx.x;
    const float *pa, *pb; int r;
    if (l < N1)            { pa = h11; pb = h12; r = l; }
    else if (l < N1 + N2)  { pa = h21; pb = h22; r = l - N1; }
    else                   { pa = h31; pb = h32; r = l - N1 - N2; }
    for (int j = threadIdx.x; j < 768; j += 256) {
        float v;
        if (j < 256)      v = pa[r * 256 + j];
        else if (j < 512) v = pb[r * 256 + (j - 256)];
        else              v = tmpP[l * 256 + (j - 512)];
        lecat[(long)l * 768 + j] = v;
    }
}

// Row softmax over S=512, in place. One block per (b,l) row.
__global__ __launch_bounds__(256) void softmax512(float* __restrict__ att)
{
    __shared__ float red[256];
    float* row = att + (long)blockIdx.x * 512;
    int t = threadIdx.x;
    float a = row[t], b = row[t + 256];
    red[t] = fmaxf(a, b);
    __syncthreads();
    for (int s = 128; s > 0; s >>= 1) {
        if (t < s) red[t] = fmaxf(red[t], red[t + s]);
        __syncthreads();
    }
    float m = red[0];
    __syncthreads();
    float ea = __expf(a - m), eb = __expf(b - m);
    red[t] = ea + eb;
    __syncthreads();
    for (int s = 128; s > 0; s >>= 1) {
        if (t < s) red[t] += red[t + s];
        __syncthreads();
    }
    float inv = 1.f / red[0];
    row[t] = ea * inv;
    row[t + 256] = eb * inv;
}

__global__ __launch_bounds__(256) void zero_kernel(float* __restrict__ p, int n)
{
    int i = blockIdx.x * 256 + threadIdx.x;
    if (i < n) p[i] = 0.f;
}

__global__ __launch_bounds__(256) void out_final(
    const float* __restrict__ acc, const float* __restrict__ ob,
    float* __restrict__ out, int total)
{
    int i = blockIdx.x * 256 + threadIdx.x;
    if (i < total) {
        float v = acc[i] + ob[i % L];
        out[i] = 1.f / (1.f + __expf(-v));
    }
}

extern "C" void kernel_launch(void* const* d_in, const int* in_sizes, int n_in,
                              void* d_out, int out_size, void* d_ws, size_t ws_size,
                              hipStream_t stream)
{
    (void)in_sizes; (void)n_in; (void)out_size; (void)ws_size;
    const int*   inputs      = (const int*)d_in[0];
    const float* text_hidden = (const float*)d_in[1];
    const float* label_enc   = (const float*)d_in[2];
    const float* w12   = (const float*)d_in[3];
    const float* w23   = (const float*)d_in[4];
    const float* fre12 = (const float*)d_in[5];
    const float* fre23 = (const float*)d_in[6];
    const float* wi1_W = (const float*)d_in[7],  *wi1_b = (const float*)d_in[8];
    const float* wf1_W = (const float*)d_in[9],  *wf1_b = (const float*)d_in[10];
    const float* wo1_W = (const float*)d_in[11], *wo1_b = (const float*)d_in[12];
    const float* wu1_W = (const float*)d_in[13], *wu1_b = (const float*)d_in[14];
    const float* wi2_W = (const float*)d_in[15], *wi2_b = (const float*)d_in[16];
    const float* wf2_W = (const float*)d_in[17], *wf2_b = (const float*)d_in[18];
    const float* wo2_W = (const float*)d_in[19], *wo2_b = (const float*)d_in[20];
    const float* wu2_W = (const float*)d_in[21], *wu2_b = (const float*)d_in[22];
    const float* ui1_W = (const float*)d_in[23], *uf1_W = (const float*)d_in[24];
    const float* uo1_W = (const float*)d_in[25], *uu1_W = (const float*)d_in[26];
    const float* ui2_W = (const float*)d_in[27], *uf2_W = (const float*)d_in[28];
    const float* uo2_W = (const float*)d_in[29], *uu2_W = (const float*)d_in[30];
    const float* mix_W = (const float*)d_in[31], *mix_b = (const float*)d_in[32];
    const float* tt_W  = (const float*)d_in[33], *tt_b  = (const float*)d_in[34];
    const float* Amat  = (const float*)d_in[35], *Wp    = (const float*)d_in[36];
    const float* out_W = (const float*)d_in[37], *out_b = (const float*)d_in[38];
    float* out = (float*)d_out;

    const float* v1 = label_enc;
    const float* v2 = label_enc + N1 * H;
    const float* v3 = label_enc + (N1 + N2) * H;

    // ---- workspace bump allocator ----
    float* ws = (float*)d_ws;
    float* text   = ws; ws += (long)B * S * H;
    float* att    = ws; ws += (long)B * L * S;
    float* feat   = ws; ws += (long)B * L * H;
    float* le     = ws; ws += L * H;
    float* AL     = ws; ws += L * H;
    float* tmpP   = ws; ws += L * H;
    float* lecat  = ws; ws += L * 768;
    float* h11  = ws; ws += N1 * H;   float* c11  = ws; ws += N1 * H;
    float* h21  = ws; ws += N2 * H;   float* c21  = ws; ws += N2 * H;
    float* h21t = ws; ws += N2 * H;   float* c21p = ws; ws += N2 * H;
    float* h31  = ws; ws += N3 * H;   float* c31  = ws; ws += N3 * H;
    float* h31t = ws; ws += N3 * H;   float* c31p = ws; ws += N3 * H;
    float* h32  = ws; ws += N3 * H;   float* c32  = ws; ws += N3 * H;
    float* h22  = ws; ws += N2 * H;   float* c22  = ws; ws += N2 * H;
    float* h22t = ws; ws += N2 * H;   float* wv2  = ws; ws += N3 * H;
    float* fcb  = ws; ws += N3 * H;   float* add22= ws; ws += N2 * H;
    float* h12  = ws; ws += N1 * H;   float* c12s = ws; ws += N1 * H;
    float* h12t = ws; ws += N1 * H;   float* wv1  = ws; ws += N2 * H;
    float* fc2b = ws; ws += N2 * H;   float* add12= ws; ws += N1 * H;
    float* outacc = ws; ws += B * L;

    // ---- 1. text = tanh(text_hidden @ tt_W + tt_b)  (M=32768,N=256,K=768) ----
    gemm64<1, false, true, false><<<dim3(H / 64, (B * S) / 64, 1), 256, 0, stream>>>(
        text_hidden, 768, 0, tt_W, H, 0, text, H, 0,
        B * S, H, 768, tt_b, nullptr, 0, 0);

    // ---- 2. label path ----
    lstm_gates<<<N1, 256, 0, stream>>>(v1, nullptr,
        wi1_W, wi1_b, wo1_W, wo1_b, wu1_W, wu1_b, nullptr, nullptr,
        nullptr, nullptr, nullptr, nullptr, nullptr, h11, c11, 0);
    small_mm<<<dim3(4, N2), 256, 0, stream>>>(w12, 1, N2, h11, H,
        nullptr, 0, 0, nullptr, 0, nullptr, nullptr, h21t, H, N1, 0, 0);
    small_mm<<<dim3(4, N2), 256, 0, stream>>>(w12, 1, N2, c11, H,
        nullptr, 0, 0, nullptr, 0, nullptr, nullptr, c21p, H, N1, 0, 0);
    lstm_gates<<<N2, 256, 0, stream>>>(v2, h21t,
        wi1_W, wi1_b, wo1_W, wo1_b, wu1_W, wu1_b, wf1_W, wf1_b,
        ui1_W, uo1_W, uu1_W, uf1_W, c21p, h21, c21, 1);
    small_mm<<<dim3(4, N3), 256, 0, stream>>>(w23, 1, N3, h21, H,
        nullptr, 0, 0, nullptr, 0, nullptr, nullptr, h31t, H, N2, 0, 0);
    small_mm<<<dim3(4, N3), 256, 0, stream>>>(w23, 1, N3, c21, H,
        nullptr, 0, 0, nullptr, 0, nullptr, nullptr, c31p, H, N2, 0, 0);
    lstm_gates<<<N3, 256, 0, stream>>>(v3, h31t,
        wi1_W, wi1_b, wo1_W, wo1_b, wu1_W, wu1_b, wf1_W, wf1_b,
        ui1_W, uo1_W, uu1_W, uf1_W, c31p, h31, c31, 1);
    lstm_gates<<<N3, 256, 0, stream>>>(v3, nullptr,
        wi2_W, wi2_b, wo2_W, wo2_b, wu2_W, wu2_b, nullptr, nullptr,
        nullptr, nullptr, nullptr, nullptr, nullptr, h32, c32, 0);
    small_mm<<<dim3(4, N2), 256, 0, stream>>>(fre23, N3, 1, h32, H,
        nullptr, 0, 0, nullptr, 0, nullptr, nullptr, h22t, H, N3, 0, 0);
    small_mm<<<dim3(4, N3), 256, 0, stream>>>(w23, 1, N3, v2, H,
        nullptr, 0, 0, nullptr, 0, nullptr, nullptr, wv2, H, N2, 0, 0);
    small_mm<<<dim3(4, N3), 256, 0, stream>>>(wv2, H, 1, wf2_W, H,
        h32, H, 1, uf2_W, H, wf2_b, c32, fcb, H, H, H, 2);
    small_mm<<<dim3(4, N2), 256, 0, stream>>>(w23, N3, 1, fcb, H,
        nullptr, 0, 0, nullptr, 0, nullptr, nullptr, add22, H, N3, 0, 0);
    lstm_gates<<<N2, 256, 0, stream>>>(v2, h22t,
        wi2_W, wi2_b, wo2_W, wo2_b, wu2_W, wu2_b, nullptr, nullptr,
        ui2_W, uo2_W, uu2_W, nullptr, add22, h22, c22, 2);
    small_mm<<<dim3(4, N1), 256, 0, stream>>>(fre12, N2, 1, h22, H,
        nullptr, 0, 0, nullptr, 0, nullptr, nullptr, h12t, H, N2, 0, 0);
    small_mm<<<dim3(4, N2), 256, 0, stream>>>(w12, 1, N2, v1, H,
        nullptr, 0, 0, nullptr, 0, nullptr, nullptr, wv1, H, N1, 0, 0);
    small_mm<<<dim3(4, N2), 256, 0, stream>>>(wv1, H, 1, wf2_W, H,
        h22, H, 1, uf2_W, H, wf2_b, c22, fc2b, H, H, H, 2);
    small_mm<<<dim3(4, N1), 256, 0, stream>>>(w12, N2, 1, fc2b, H,
        nullptr, 0, 0, nullptr, 0, nullptr, nullptr, add12, H, N2, 0, 0);
    lstm_gates<<<N1, 256, 0, stream>>>(v1, h12t,
        wi2_W, wi2_b, wo2_W, wo2_b, wu2_W, wu2_b, nullptr, nullptr,
        ui2_W, uo2_W, uu2_W, nullptr, add12, h12, c12s, 2);
    // S7: temp = relu(A @ label_enc @ Wp); le = [h|temp] @ mix_W + mix_b
    small_mm<<<dim3(4, L), 256, 0, stream>>>(Amat, L, 1, label_enc, H,
        nullptr, 0, 0, nullptr, 0, nullptr, nullptr, AL, H, L, 0, 0);
    small_mm<<<dim3(4, L), 256, 0, stream>>>(AL, H, 1, Wp, H,
        nullptr, 0, 0, nullptr, 0, nullptr, nullptr, tmpP, H, H, 0, 1);
    build_lecat<<<L, 256, 0, stream>>>(h11, h12, h21, h22, h31, h32, tmpP, lecat);
    small_mm<<<dim3(4, L), 256, 0, stream>>>(lecat, 768, 1, mix_W, H,
        nullptr, 0, 0, nullptr, 0, mix_b, nullptr, le, H, 768, 0, 0);

    // ---- 3. logits: att[b,l,s] = le @ text[b]^T + pad  (batched over b) ----
    gemm64<2, true, true, false><<<dim3(S / 64, (L + 63) / 64, B), 256, 0, stream>>>(
        le, H, 0, text, H, (long)S * H, att, S, (long)L * S,
        L, S, H, nullptr, inputs, S, 0);

    // ---- 4. softmax over s ----
    softmax512<<<B * L, 256, 0, stream>>>(att);

    // ---- 5. feat[b,l,:] = att[b] @ text[b]  (batched) ----
    gemm64<0, false, true, false><<<dim3(H / 64, (L + 63) / 64, B), 256, 0, stream>>>(
        att, S, (long)L * S, text, H, (long)S * H, feat, H, (long)L * H,
        L, H, S, nullptr, nullptr, 0, 0);

    // ---- 6. out = sig(feat(64x36096) @ out_W + out_b): K-split + atomics ----
    zero_kernel<<<(B * L + 255) / 256, 256, 0, stream>>>(outacc, B * L);
    gemm64<3, false, false, true><<<dim3((L + 63) / 64, 1, 24), 256, 0, stream>>>(
        feat, L * H, 0, out_W, L, 0, outacc, L, 0,
        B, L, L * H, nullptr, nullptr, 0, 1504);
    out_final<<<(B * L + 255) / 256, 256, 0, stream>>>(outacc, out_b, out, B * L);
}

// Round 4
// 796.020 us; speedup vs baseline: 2.3165x; 1.2292x over previous
//
#include <hip/hip_runtime.h>
#include <math.h>

// Problem constants
static constexpr int H = 256, L = 141, N1 = 9, N2 = 34, N3 = 98;
static constexpr int B = 64, S = 512;

typedef __attribute__((ext_vector_type(8))) _Float16 f16x8;
typedef __attribute__((ext_vector_type(4))) float f32x4;

__device__ inline unsigned short f2h(float x) {
    _Float16 h = (_Float16)x;
    return __builtin_bit_cast(unsigned short, h);
}

__device__ inline void gload_lds16(const void* g, void* l) {
    __builtin_amdgcn_global_load_lds(
        (const __attribute__((address_space(1))) void*)g,
        (__attribute__((address_space(3))) void*)l, 16, 0, 0);
}

// ---------------------------------------------------------------------------
// MFMA fp16 GEMM, m93/m97 structure: 128x128 tile, BK=32, 16x16x32_f16,
// 256 threads = 4 waves, each wave a 64x64 subtile (4x4 of 16x16).
// A: [M][K] k-contiguous (f16, or fp32 if CONVA). B: [N][K] k-contiguous f16.
// Layouts (dtype-independent, m121-m128): A/B-frag [idx=lane&15][k=quad*8+j];
// C/D col=lane&15, row=quad*4+reg. A rows clamped to M-1; N,K exact.
// EPI: 0 = store fp32 C. 1 = tanh(acc+bias[n]) -> text_h[m][n] (f16 bits) and
//      text_hT[(b*256+n)*512+s] (b=m>>9, s=m&511). 2 = pad-mask + store fp32.
// ---------------------------------------------------------------------------
template<int EPI, bool CONVA>
__global__ __launch_bounds__(256) void gemm_mfma(
    const void* __restrict__ Aptr, int lda, long strA,
    const unsigned short* __restrict__ Bp, int ldb, long strB,
    float* __restrict__ C, int ldc, long strC,
    int M, int N, int K,
    const float* __restrict__ bias,
    const int* __restrict__ tokens,
    unsigned short* __restrict__ outH,
    unsigned short* __restrict__ outHT)
{
    __shared__ unsigned short A_s[128 * 32];
    __shared__ unsigned short B_s[128 * 32];
    const int tid  = threadIdx.x;
    const int wave = tid >> 6, lane = tid & 63;
    const int quad = lane >> 4, l16 = lane & 15;
    const int bz = blockIdx.z;
    const int m0 = blockIdx.y * 128, n0 = blockIdx.x * 128;
    const int wm = (wave & 1) * 64, wn = (wave >> 1) * 64;

    const unsigned short* Bb = Bp + (long)bz * strB;

    f32x4 acc[4][4] = {};

    for (int k0 = 0; k0 < K; k0 += 32) {
        // ---- stage A ----
        if (CONVA) {
            const float* Af = (const float*)Aptr + (long)bz * strA;
            #pragma unroll
            for (int it = 0; it < 4; it++) {
                int idx = it * 256 + tid;
                int row = idx >> 3, col4 = idx & 7;
                int gm = m0 + row; if (gm > M - 1) gm = M - 1;
                float4 v = *(const float4*)(Af + (long)gm * lda + k0 + col4 * 4);
                unsigned int p0 = f2h(v.x) | ((unsigned int)f2h(v.y) << 16);
                unsigned int p1 = f2h(v.z) | ((unsigned int)f2h(v.w) << 16);
                *(uint2*)&A_s[row * 32 + col4 * 4] = make_uint2(p0, p1);
            }
        } else {
            const unsigned short* Ab = (const unsigned short*)Aptr + (long)bz * strA;
            #pragma unroll
            for (int t = 0; t < 2; t++) {
                int rowb = wave * 32 + t * 16;
                int gm = m0 + rowb + (lane >> 2); if (gm > M - 1) gm = M - 1;
                gload_lds16(Ab + (long)gm * lda + k0 + (lane & 3) * 8,
                            &A_s[rowb * 32]);
            }
        }
        // ---- stage B ----
        #pragma unroll
        for (int t = 0; t < 2; t++) {
            int rowb = wave * 32 + t * 16;
            int gn = n0 + rowb + (lane >> 2);
            gload_lds16(Bb + (long)gn * ldb + k0 + (lane & 3) * 8,
                        &B_s[rowb * 32]);
        }
        __syncthreads();
        // ---- fragments + MFMA ----
        f16x8 a[4], b[4];
        #pragma unroll
        for (int i = 0; i < 4; i++)
            a[i] = *(const f16x8*)&A_s[(wm + i * 16 + l16) * 32 + quad * 8];
        #pragma unroll
        for (int j = 0; j < 4; j++)
            b[j] = *(const f16x8*)&B_s[(wn + j * 16 + l16) * 32 + quad * 8];
        #pragma unroll
        for (int i = 0; i < 4; i++)
            #pragma unroll
            for (int j = 0; j < 4; j++)
                acc[i][j] = __builtin_amdgcn_mfma_f32_16x16x32_f16(
                    a[i], b[j], acc[i][j], 0, 0, 0);
        __syncthreads();
    }

    // ---- epilogue ----
    #pragma unroll
    for (int i = 0; i < 4; i++) {
        #pragma unroll
        for (int j = 0; j < 4; j++) {
            #pragma unroll
            for (int r = 0; r < 4; r++) {
                int gm = m0 + wm + i * 16 + quad * 4 + r;
                int gn = n0 + wn + j * 16 + l16;
                if (gm >= M || gn >= N) continue;
                float v = acc[i][j][r];
                if (EPI == 0) {
                    C[(long)bz * strC + (long)gm * ldc + gn] = v;
                } else if (EPI == 1) {
                    v = tanhf(v + bias[gn]);
                    unsigned short hv = f2h(v);
                    outH[(long)gm * ldc + gn] = hv;
                    int bb = gm >> 9, s = gm & 511;
                    outHT[((long)bb * 256 + gn) * 512 + s] = hv;
                } else { // EPI == 2
                    int tok = tokens[(long)bz * 512 + gn];
                    if (tok == 0 || tok == 101 || tok == 102) v -= 1e30f;
                    C[(long)bz * strC + (long)gm * ldc + gn] = v;
                }
            }
        }
    }
}

// ---------------------------------------------------------------------------
// fp32 GEMM (kept for the out-head K-split). See round-2 comments.
// ---------------------------------------------------------------------------
template<int EPI, bool TRANSB, bool BVEC, bool KSPLIT>
__global__ __launch_bounds__(256) void gemm64(
    const float* __restrict__ A, int lda, long strA,
    const float* __restrict__ Bm, int ldb, long strB,
    float* __restrict__ C, int ldc, long strC,
    int M, int N, int K,
    const float* __restrict__ aux, const int* __restrict__ mask, int maskStride,
    int kChunk)
{
    __shared__ float As[16][64];
    __shared__ float Bs[16][64];
    const int tid = threadIdx.x;
    const int bz  = blockIdx.z;
    long aOff, bOff, cOff;
    int kBeg, kEnd;
    if (KSPLIT) {
        aOff = bOff = cOff = 0;
        kBeg = bz * kChunk;
        kEnd = kBeg + kChunk; if (kEnd > K) kEnd = K;
    } else {
        aOff = (long)bz * strA; bOff = (long)bz * strB; cOff = (long)bz * strC;
        kBeg = 0; kEnd = K;
    }
    const int m0 = blockIdx.y * 64, n0 = blockIdx.x * 64;
    const int ty = tid >> 4, tx = tid & 15;
    const int am = tid >> 2, akq = tid & 3;
    float acc[4][4] = {};

    for (int kk = kBeg; kk < kEnd; kk += 16) {
        {
            float4 v = make_float4(0.f, 0.f, 0.f, 0.f);
            int m = m0 + am;
            if (m < M) v = *(const float4*)(A + aOff + (long)m * lda + (kk + akq * 4));
            As[akq*4+0][am] = v.x; As[akq*4+1][am] = v.y;
            As[akq*4+2][am] = v.z; As[akq*4+3][am] = v.w;
        }
        if (!TRANSB) {
            if (BVEC) {
                int k = tid >> 4, n = (tid & 15) << 2;
                float4 v = *(const float4*)(Bm + bOff + (long)(kk + k) * ldb + (n0 + n));
                *(float4*)&Bs[k][n] = v;
            } else {
                #pragma unroll
                for (int i = 0; i < 4; i++) {
                    int idx = tid + i * 256;
                    int k = idx >> 6, n = idx & 63;
                    float v = 0.f;
                    if (n0 + n < N) v = Bm[bOff + (long)(kk + k) * ldb + (n0 + n)];
                    Bs[k][n] = v;
                }
            }
        } else {
            float4 v = make_float4(0.f, 0.f, 0.f, 0.f);
            int n = n0 + am;
            if (n < N) v = *(const float4*)(Bm + bOff + (long)n * ldb + (kk + akq * 4));
            Bs[akq*4+0][am] = v.x; Bs[akq*4+1][am] = v.y;
            Bs[akq*4+2][am] = v.z; Bs[akq*4+3][am] = v.w;
        }
        __syncthreads();
        #pragma unroll
        for (int k = 0; k < 16; k++) {
            float4 a4 = *(const float4*)&As[k][ty << 2];
            float4 b4 = *(const float4*)&Bs[k][tx << 2];
            float av[4] = {a4.x, a4.y, a4.z, a4.w};
            float bv[4] = {b4.x, b4.y, b4.z, b4.w};
            #pragma unroll
            for (int i = 0; i < 4; i++)
                #pragma unroll
                for (int j = 0; j < 4; j++)
                    acc[i][j] += av[i] * bv[j];
        }
        __syncthreads();
    }
    #pragma unroll
    for (int i = 0; i < 4; i++) {
        int m = m0 + (ty << 2) + i;
        if (m >= M) continue;
        #pragma unroll
        for (int j = 0; j < 4; j++) {
            int n = n0 + (tx << 2) + j;
            if (n >= N) continue;
            float v = acc[i][j];
            if (EPI == 1) v = tanhf(v + aux[n]);
            if (EPI == 2) {
                int tok = mask[(long)bz * maskStride + n];
                if (tok == 0 || tok == 101 || tok == 102) v -= 1e30f;
            }
            if (EPI == 3) atomicAdd(C + cOff + (long)m * ldc + n, v);
            else          C[cOff + (long)m * ldc + n] = v;
        }
    }
}

// ---------------------------------------------------------------------------
// Latency-optimized small matmul (see round-2 comments).
// ---------------------------------------------------------------------------
__global__ __launch_bounds__(256) void small_mm(
    const float* __restrict__ A, int sAm, int sAk,
    const float* __restrict__ Bp, int sBk,
    const float* __restrict__ A2, int sA2m, int sA2k,
    const float* __restrict__ B2, int sB2k,
    const float* __restrict__ bias,
    const float* __restrict__ mulsrc,
    float* __restrict__ C,
    int N, int K, int K2, int act)
{
    __shared__ float As[768];
    __shared__ float As2[256];
    __shared__ float red[256];
    const int tid = threadIdx.x;
    const int m = blockIdx.y;
    const int nl = tid & 63, ks = tid >> 6;
    const int n = blockIdx.x * 64 + nl;

    for (int k = tid; k < K; k += 256)
        As[k] = A[(long)m * sAm + (long)k * sAk];
    if (A2)
        for (int k = tid; k < K2; k += 256)
            As2[k] = A2[(long)m * sA2m + (long)k * sA2k];
    __syncthreads();

    float a0 = 0.f, a1 = 0.f, a2 = 0.f, a3 = 0.f;
    {
        int k = ks;
        for (; k + 12 < K; k += 16) {
            float b0 = Bp[(long)(k     ) * sBk + n];
            float b1 = Bp[(long)(k +  4) * sBk + n];
            float b2 = Bp[(long)(k +  8) * sBk + n];
            float b3 = Bp[(long)(k + 12) * sBk + n];
            a0 += As[k] * b0;  a1 += As[k + 4] * b1;
            a2 += As[k + 8] * b2;  a3 += As[k + 12] * b3;
        }
        for (; k < K; k += 4)
            a0 += As[k] * Bp[(long)k * sBk + n];
    }
    if (A2) {
        int k = ks;
        for (; k + 12 < K2; k += 16) {
            float b0 = B2[(long)(k     ) * sB2k + n];
            float b1 = B2[(long)(k +  4) * sB2k + n];
            float b2 = B2[(long)(k +  8) * sB2k + n];
            float b3 = B2[(long)(k + 12) * sB2k + n];
            a0 += As2[k] * b0;  a1 += As2[k + 4] * b1;
            a2 += As2[k + 8] * b2;  a3 += As2[k + 12] * b3;
        }
        for (; k < K2; k += 4)
            a0 += As2[k] * B2[(long)k * sB2k + n];
    }
    red[tid] = a0 + a1 + a2 + a3;
    __syncthreads();
    if (ks == 0 && n < N) {
        float acc = red[nl] + red[64 + nl] + red[128 + nl] + red[192 + nl];
        if (bias) acc += bias[n];
        if (act == 1) acc = fmaxf(acc, 0.f);
        else if (act == 2) acc = 1.f / (1.f + __expf(-acc));
        if (mulsrc) acc *= mulsrc[(long)m * N + n];
        C[(long)m * N + n] = acc;
    }
}

// ---------------------------------------------------------------------------
// Fused LSTM-gates, unroll-4 (see round-2 comments).
// ---------------------------------------------------------------------------
__global__ __launch_bounds__(256) void lstm_gates(
    const float* __restrict__ X, const float* __restrict__ Xu,
    const float* __restrict__ Wi, const float* __restrict__ bi,
    const float* __restrict__ Wo, const float* __restrict__ bo,
    const float* __restrict__ Wu, const float* __restrict__ bu,
    const float* __restrict__ Wf, const float* __restrict__ bf,
    const float* __restrict__ Ui, const float* __restrict__ Uo,
    const float* __restrict__ Uu, const float* __restrict__ Uf,
    const float* __restrict__ cmod,
    float* __restrict__ h, float* __restrict__ c, int mode)
{
    __shared__ float xs[256], xus[256];
    int m = blockIdx.x, n = threadIdx.x;
    xs[n] = X[m * 256 + n];
    if (Xu) xus[n] = Xu[m * 256 + n];
    __syncthreads();
    float gi = bi[n], go = bo[n], gu = bu[n];
    float gf = Wf ? bf[n] : 0.f;
    for (int k = 0; k < 256; k += 4) {
        float x0 = xs[k], x1 = xs[k+1], x2 = xs[k+2], x3 = xs[k+3];
        long o = (long)k * 256 + n;
        float i0 = Wi[o], i1 = Wi[o+256], i2 = Wi[o+512], i3 = Wi[o+768];
        float q0 = Wo[o], q1 = Wo[o+256], q2 = Wo[o+512], q3 = Wo[o+768];
        float u0 = Wu[o], u1 = Wu[o+256], u2 = Wu[o+512], u3 = Wu[o+768];
        gi += x0*i0 + x1*i1 + x2*i2 + x3*i3;
        go += x0*q0 + x1*q1 + x2*q2 + x3*q3;
        gu += x0*u0 + x1*u1 + x2*u2 + x3*u3;
        if (Wf) {
            float f0 = Wf[o], f1 = Wf[o+256], f2 = Wf[o+512], f3 = Wf[o+768];
            gf += x0*f0 + x1*f1 + x2*f2 + x3*f3;
        }
    }
    if (Ui) {
        for (int k = 0; k < 256; k += 4) {
            float x0 = xus[k], x1 = xus[k+1], x2 = xus[k+2], x3 = xus[k+3];
            long o = (long)k * 256 + n;
            float i0 = Ui[o], i1 = Ui[o+256], i2 = Ui[o+512], i3 = Ui[o+768];
            float q0 = Uo[o], q1 = Uo[o+256], q2 = Uo[o+512], q3 = Uo[o+768];
            float u0 = Uu[o], u1 = Uu[o+256], u2 = Uu[o+512], u3 = Uu[o+768];
            gi += x0*i0 + x1*i1 + x2*i2 + x3*i3;
            go += x0*q0 + x1*q1 + x2*q2 + x3*q3;
            gu += x0*u0 + x1*u1 + x2*u2 + x3*u3;
            if (Uf) {
                float f0 = Uf[o], f1 = Uf[o+256], f2 = Uf[o+512], f3 = Uf[o+768];
                gf += x0*f0 + x1*f1 + x2*f2 + x3*f3;
            }
        }
    }
    float iv = 1.f / (1.f + __expf(-gi));
    float ov = 1.f / (1.f + __expf(-go));
    float uv = tanhf(gu);
    float cv = iv * uv;
    if (mode == 1)      cv += (1.f / (1.f + __expf(-gf))) * cmod[m * 256 + n];
    else if (mode == 2) cv += cmod[m * 256 + n];
    h[m * 256 + n] = ov * tanhf(cv);
    c[m * 256 + n] = cv;
}

// Build le_cat (141 x 768) = [h1x | h2x | temp]
__global__ __launch_bounds__(256) void build_lecat(
    const float* __restrict__ h11, const float* __restrict__ h12,
    const float* __restrict__ h21, const float* __restrict__ h22,
    const float* __restrict__ h31, const float* __restrict__ h32,
    const float* __restrict__ tmpP, float* __restrict__ lecat)
{
    int l = blockIdx.x;
    const float *pa, *pb; int r;
    if (l < N1)            { pa = h11; pb = h12; r = l; }
    else if (l < N1 + N2)  { pa = h21; pb = h22; r = l - N1; }
    else                   { pa = h31; pb = h32; r = l - N1 - N2; }
    for (int j = threadIdx.x; j < 768; j += 256) {
        float v;
        if (j < 256)      v = pa[r * 256 + j];
        else if (j < 512) v = pb[r * 256 + (j - 256)];
        else              v = tmpP[l * 256 + (j - 512)];
        lecat[(long)l * 768 + j] = v;
    }
}

// Row softmax over S=512; reads fp32, writes fp16 attention weights.
__global__ __launch_bounds__(256) void softmax512(
    const float* __restrict__ att, unsigned short* __restrict__ atth)
{
    __shared__ float red[256];
    const float* row = att + (long)blockIdx.x * 512;
    unsigned short* orow = atth + (long)blockIdx.x * 512;
    int t = threadIdx.x;
    float a = row[t], b = row[t + 256];
    red[t] = fmaxf(a, b);
    __syncthreads();
    for (int s = 128; s > 0; s >>= 1) {
        if (t < s) red[t] = fmaxf(red[t], red[t + s]);
        __syncthreads();
    }
    float m = red[0];
    __syncthreads();
    float ea = __expf(a - m), eb = __expf(b - m);
    red[t] = ea + eb;
    __syncthreads();
    for (int s = 128; s > 0; s >>= 1) {
        if (t < s) red[t] += red[t + s];
        __syncthreads();
    }
    float inv = 1.f / red[0];
    orow[t] = f2h(ea * inv);
    orow[t + 256] = f2h(eb * inv);
}

// fp32 -> fp16 elementwise
__global__ __launch_bounds__(256) void conv_f2h(
    const float* __restrict__ src, unsigned short* __restrict__ dst, int n)
{
    int i = blockIdx.x * 256 + threadIdx.x;
    if (i < n) dst[i] = f2h(src[i]);
}

// tt_W (768x256 fp32, [k][n]) -> tt_Wt (256x768 fp16, [n][k])
__global__ __launch_bounds__(256) void transp_conv768(
    const float* __restrict__ src, unsigned short* __restrict__ dst)
{
    int idx = blockIdx.x * 256 + threadIdx.x;   // total 196608
    int n = idx / 768, k = idx - n * 768;
    dst[idx] = f2h(src[(long)k * 256 + n]);
}

__global__ __launch_bounds__(256) void zero_kernel(float* __restrict__ p, int n)
{
    int i = blockIdx.x * 256 + threadIdx.x;
    if (i < n) p[i] = 0.f;
}

__global__ __launch_bounds__(256) void out_final(
    const float* __restrict__ acc, const float* __restrict__ ob,
    float* __restrict__ out, int total)
{
    int i = blockIdx.x * 256 + threadIdx.x;
    if (i < total) {
        float v = acc[i] + ob[i % L];
        out[i] = 1.f / (1.f + __expf(-v));
    }
}

extern "C" void kernel_launch(void* const* d_in, const int* in_sizes, int n_in,
                              void* d_out, int out_size, void* d_ws, size_t ws_size,
                              hipStream_t stream)
{
    (void)in_sizes; (void)n_in; (void)out_size; (void)ws_size;
    const int*   inputs      = (const int*)d_in[0];
    const float* text_hidden = (const float*)d_in[1];
    const float* label_enc   = (const float*)d_in[2];
    const float* w12   = (const float*)d_in[3];
    const float* w23   = (const float*)d_in[4];
    const float* fre12 = (const float*)d_in[5];
    const float* fre23 = (const float*)d_in[6];
    const float* wi1_W = (const float*)d_in[7],  *wi1_b = (const float*)d_in[8];
    const float* wf1_W = (const float*)d_in[9],  *wf1_b = (const float*)d_in[10];
    const float* wo1_W = (const float*)d_in[11], *wo1_b = (const float*)d_in[12];
    const float* wu1_W = (const float*)d_in[13], *wu1_b = (const float*)d_in[14];
    const float* wi2_W = (const float*)d_in[15], *wi2_b = (const float*)d_in[16];
    const float* wf2_W = (const float*)d_in[17], *wf2_b = (const float*)d_in[18];
    const float* wo2_W = (const float*)d_in[19], *wo2_b = (const float*)d_in[20];
    const float* wu2_W = (const float*)d_in[21], *wu2_b = (const float*)d_in[22];
    const float* ui1_W = (const float*)d_in[23], *uf1_W = (const float*)d_in[24];
    const float* uo1_W = (const float*)d_in[25], *uu1_W = (const float*)d_in[26];
    const float* ui2_W = (const float*)d_in[27], *uf2_W = (const float*)d_in[28];
    const float* uo2_W = (const float*)d_in[29], *uu2_W = (const float*)d_in[30];
    const float* mix_W = (const float*)d_in[31], *mix_b = (const float*)d_in[32];
    const float* tt_W  = (const float*)d_in[33], *tt_b  = (const float*)d_in[34];
    const float* Amat  = (const float*)d_in[35], *Wp    = (const float*)d_in[36];
    const float* out_W = (const float*)d_in[37], *out_b = (const float*)d_in[38];
    float* out = (float*)d_out;

    const float* v1 = label_enc;
    const float* v2 = label_enc + N1 * H;
    const float* v3 = label_enc + (N1 + N2) * H;

    // ---- workspace bump allocator (float-granular; all chunks 16B-aligned) ----
    float* ws = (float*)d_ws;
    float* att    = ws; ws += (long)B * L * S;             // fp32 logits/softmax in
    float* feat   = ws; ws += (long)B * L * H;             // fp32 features
    unsigned short* text_h  = (unsigned short*)ws; ws += (long)B * S * H / 2;  // [b*s][h]
    unsigned short* text_hT = (unsigned short*)ws; ws += (long)B * S * H / 2;  // [b][h][s]
    unsigned short* att_h   = (unsigned short*)ws; ws += (long)B * L * S / 2;
    unsigned short* tt_Wt   = (unsigned short*)ws; ws += 768 * H / 2;
    unsigned short* le_h    = (unsigned short*)ws; ws += (L * H) / 2 + 4;
    float* le     = ws; ws += L * H;
    float* AL     = ws; ws += L * H;
    float* tmpP   = ws; ws += L * H;
    float* lecat  = ws; ws += L * 768;
    float* h11  = ws; ws += N1 * H;   float* c11  = ws; ws += N1 * H;
    float* h21  = ws; ws += N2 * H;   float* c21  = ws; ws += N2 * H;
    float* h21t = ws; ws += N2 * H;   float* c21p = ws; ws += N2 * H;
    float* h31  = ws; ws += N3 * H;   float* c31  = ws; ws += N3 * H;
    float* h31t = ws; ws += N3 * H;   float* c31p = ws; ws += N3 * H;
    float* h32  = ws; ws += N3 * H;   float* c32  = ws; ws += N3 * H;
    float* h22  = ws; ws += N2 * H;   float* c22  = ws; ws += N2 * H;
    float* h22t = ws; ws += N2 * H;   float* wv2  = ws; ws += N3 * H;
    float* fcb  = ws; ws += N3 * H;   float* add22= ws; ws += N2 * H;
    float* h12  = ws; ws += N1 * H;   float* c12s = ws; ws += N1 * H;
    float* h12t = ws; ws += N1 * H;   float* wv1  = ws; ws += N2 * H;
    float* fc2b = ws; ws += N2 * H;   float* add12= ws; ws += N1 * H;
    float* outacc = ws; ws += B * L;

    // ---- 0. tt_W -> fp16 transposed ----
    transp_conv768<<<768 * H / 256, 256, 0, stream>>>(tt_W, tt_Wt);

    // ---- 1. text = tanh(text_hidden @ tt_W + tt_b), fp16 out (both layouts) ----
    gemm_mfma<1, true><<<dim3(H / 128, (B * S) / 128, 1), 256, 0, stream>>>(
        text_hidden, 768, 0, tt_Wt, 768, 0, nullptr, H, 0,
        B * S, H, 768, tt_b, nullptr, text_h, text_hT);

    // ---- 2. label path (fp32, latency-optimized) ----
    lstm_gates<<<N1, 256, 0, stream>>>(v1, nullptr,
        wi1_W, wi1_b, wo1_W, wo1_b, wu1_W, wu1_b, nullptr, nullptr,
        nullptr, nullptr, nullptr, nullptr, nullptr, h11, c11, 0);
    small_mm<<<dim3(4, N2), 256, 0, stream>>>(w12, 1, N2, h11, H,
        nullptr, 0, 0, nullptr, 0, nullptr, nullptr, h21t, H, N1, 0, 0);
    small_mm<<<dim3(4, N2), 256, 0, stream>>>(w12, 1, N2, c11, H,
        nullptr, 0, 0, nullptr, 0, nullptr, nullptr, c21p, H, N1, 0, 0);
    lstm_gates<<<N2, 256, 0, stream>>>(v2, h21t,
        wi1_W, wi1_b, wo1_W, wo1_b, wu1_W, wu1_b, wf1_W, wf1_b,
        ui1_W, uo1_W, uu1_W, uf1_W, c21p, h21, c21, 1);
    small_mm<<<dim3(4, N3), 256, 0, stream>>>(w23, 1, N3, h21, H,
        nullptr, 0, 0, nullptr, 0, nullptr, nullptr, h31t, H, N2, 0, 0);
    small_mm<<<dim3(4, N3), 256, 0, stream>>>(w23, 1, N3, c21, H,
        nullptr, 0, 0, nullptr, 0, nullptr, nullptr, c31p, H, N2, 0, 0);
    lstm_gates<<<N3, 256, 0, stream>>>(v3, h31t,
        wi1_W, wi1_b, wo1_W, wo1_b, wu1_W, wu1_b, wf1_W, wf1_b,
        ui1_W, uo1_W, uu1_W, uf1_W, c31p, h31, c31, 1);
    lstm_gates<<<N3, 256, 0, stream>>>(v3, nullptr,
        wi2_W, wi2_b, wo2_W, wo2_b, wu2_W, wu2_b, nullptr, nullptr,
        nullptr, nullptr, nullptr, nullptr, nullptr, h32, c32, 0);
    small_mm<<<dim3(4, N2), 256, 0, stream>>>(fre23, N3, 1, h32, H,
        nullptr, 0, 0, nullptr, 0, nullptr, nullptr, h22t, H, N3, 0, 0);
    small_mm<<<dim3(4, N3), 256, 0, stream>>>(w23, 1, N3, v2, H,
        nullptr, 0, 0, nullptr, 0, nullptr, nullptr, wv2, H, N2, 0, 0);
    small_mm<<<dim3(4, N3), 256, 0, stream>>>(wv2, H, 1, wf2_W, H,
        h32, H, 1, uf2_W, H, wf2_b, c32, fcb, H, H, H, 2);
    small_mm<<<dim3(4, N2), 256, 0, stream>>>(w23, N3, 1, fcb, H,
        nullptr, 0, 0, nullptr, 0, nullptr, nullptr, add22, H, N3, 0, 0);
    lstm_gates<<<N2, 256, 0, stream>>>(v2, h22t,
        wi2_W, wi2_b, wo2_W, wo2_b, wu2_W, wu2_b, nullptr, nullptr,
        ui2_W, uo2_W, uu2_W, nullptr, add22, h22, c22, 2);
    small_mm<<<dim3(4, N1), 256, 0, stream>>>(fre12, N2, 1, h22, H,
        nullptr, 0, 0, nullptr, 0, nullptr, nullptr, h12t, H, N2, 0, 0);
    small_mm<<<dim3(4, N2), 256, 0, stream>>>(w12, 1, N2, v1, H,
        nullptr, 0, 0, nullptr, 0, nullptr, nullptr, wv1, H, N1, 0, 0);
    small_mm<<<dim3(4, N2), 256, 0, stream>>>(wv1, H, 1, wf2_W, H,
        h22, H, 1, uf2_W, H, wf2_b, c22, fc2b, H, H, H, 2);
    small_mm<<<dim3(4, N1), 256, 0, stream>>>(w12, N2, 1, fc2b, H,
        nullptr, 0, 0, nullptr, 0, nullptr, nullptr, add12, H, N2, 0, 0);
    lstm_gates<<<N1, 256, 0, stream>>>(v1, h12t,
        wi2_W, wi2_b, wo2_W, wo2_b, wu2_W, wu2_b, nullptr, nullptr,
        ui2_W, uo2_W, uu2_W, nullptr, add12, h12, c12s, 2);
    small_mm<<<dim3(4, L), 256, 0, stream>>>(Amat, L, 1, label_enc, H,
        nullptr, 0, 0, nullptr, 0, nullptr, nullptr, AL, H, L, 0, 0);
    small_mm<<<dim3(4, L), 256, 0, stream>>>(AL, H, 1, Wp, H,
        nullptr, 0, 0, nullptr, 0, nullptr, nullptr, tmpP, H, H, 0, 1);
    build_lecat<<<L, 256, 0, stream>>>(h11, h12, h21, h22, h31, h32, tmpP, lecat);
    small_mm<<<dim3(4, L), 256, 0, stream>>>(lecat, 768, 1, mix_W, H,
        nullptr, 0, 0, nullptr, 0, mix_b, nullptr, le, H, 768, 0, 0);
    conv_f2h<<<(L * H + 255) / 256, 256, 0, stream>>>(le, le_h, L * H);

    // ---- 3. logits: att[b,l,s] = le_h @ text_h[b]^T + pad ----
    gemm_mfma<2, false><<<dim3(S / 128, (L + 127) / 128, B), 256, 0, stream>>>(
        le_h, H, 0, text_h, H, (long)S * H, att, S, (long)L * S,
        L, S, H, nullptr, inputs, nullptr, nullptr);

    // ---- 4. softmax (fp32 in, fp16 out) ----
    softmax512<<<B * L, 256, 0, stream>>>(att, att_h);

    // ---- 5. feat[b,l,:] = att_h[b] @ text_hT[b]^T ----
    gemm_mfma<0, false><<<dim3(H / 128, (L + 127) / 128, B), 256, 0, stream>>>(
        att_h, S, (long)L * S, text_hT, S, (long)H * S, feat, H, (long)L * H,
        L, H, S, nullptr, nullptr, nullptr, nullptr);

    // ---- 6. out = sig(feat @ out_W + out_b): fp32 K-split + atomics ----
    zero_kernel<<<(B * L + 255) / 256, 256, 0, stream>>>(outacc, B * L);
    gemm64<3, false, false, true><<<dim3((L + 63) / 64, 1, 24), 256, 0, stream>>>(
        feat, L * H, 0, out_W, L, 0, outacc, L, 0,
        B, L, L * H, nullptr, nullptr, 0, 1504);
    out_final<<<(B * L + 255) / 256, 256, 0, stream>>>(outacc, out_b, out, B * L);
}

// Round 5
// 536.309 us; speedup vs baseline: 3.4384x; 1.4843x over previous
//
#include <hip/hip_runtime.h>
#include <math.h>

// Problem constants
static constexpr int H = 256, L = 141, N1 = 9, N2 = 34, N3 = 98;
static constexpr int B = 64, S = 512;

typedef __attribute__((ext_vector_type(8))) _Float16 f16x8;
typedef __attribute__((ext_vector_type(4))) float f32x4;

__device__ inline unsigned short f2h(float x) {
    _Float16 h = (_Float16)x;
    return __builtin_bit_cast(unsigned short, h);
}
__device__ inline float sigf(float x) { return 1.f / (1.f + __expf(-x)); }

__device__ inline void gload_lds16(const void* g, void* l) {
    __builtin_amdgcn_global_load_lds(
        (const __attribute__((address_space(1))) void*)g,
        (__attribute__((address_space(3))) void*)l, 16, 0, 0);
}

// ---------------------------------------------------------------------------
// MFMA fp16 GEMM, 128x128 tile, BK=32, 16x16x32_f16, 4 waves.
// A: [M][K] k-contig (f16, or fp32 if CONVA). B: [N][K] k-contig f16.
// A rows clamped to M-1, B rows clamped to N-1 (garbage guarded in epilogue).
// EPI 0: fp32 C.     EPI 1: tanh(acc+bias[n]) -> outH[m][n] + outHT[(b*256+n)*512+s]
// EPI 2: pad-mask + fp32 C.   EPI 3: fp16 outH only.
// EPI 4: K-split (grid.z = k-chunk of kChunk) + fp32 atomicAdd into C.
// ---------------------------------------------------------------------------
template<int EPI, bool CONVA>
__global__ __launch_bounds__(256) void gemm_mfma(
    const void* __restrict__ Aptr, int lda, long strA,
    const unsigned short* __restrict__ Bp, int ldb, long strB,
    float* __restrict__ C, int ldc, long strC,
    int M, int N, int K,
    const float* __restrict__ bias,
    const int* __restrict__ tokens,
    unsigned short* __restrict__ outH,
    unsigned short* __restrict__ outHT,
    int kChunk)
{
    __shared__ unsigned short A_s[128 * 32];
    __shared__ unsigned short B_s[128 * 32];
    const int tid  = threadIdx.x;
    const int wave = tid >> 6, lane = tid & 63;
    const int quad = lane >> 4, l16 = lane & 15;
    const int bz = blockIdx.z;
    const int m0 = blockIdx.y * 128, n0 = blockIdx.x * 128;
    const int wm = (wave & 1) * 64, wn = (wave >> 1) * 64;

    long aBase, bBase;
    int kBeg, kEnd;
    if (EPI == 4) { aBase = 0; bBase = 0; kBeg = bz * kChunk; kEnd = kBeg + kChunk; }
    else { aBase = (long)bz * strA; bBase = (long)bz * strB; kBeg = 0; kEnd = K; }

    f32x4 acc[4][4] = {};

    for (int k0 = kBeg; k0 < kEnd; k0 += 32) {
        // ---- stage A ----
        if (CONVA) {
            const float* Af = (const float*)Aptr + aBase;
            #pragma unroll
            for (int it = 0; it < 4; it++) {
                int idx = it * 256 + tid;
                int row = idx >> 3, col4 = idx & 7;
                int gm = m0 + row; if (gm > M - 1) gm = M - 1;
                float4 v = *(const float4*)(Af + (long)gm * lda + k0 + col4 * 4);
                unsigned int p0 = f2h(v.x) | ((unsigned int)f2h(v.y) << 16);
                unsigned int p1 = f2h(v.z) | ((unsigned int)f2h(v.w) << 16);
                *(uint2*)&A_s[row * 32 + col4 * 4] = make_uint2(p0, p1);
            }
        } else {
            const unsigned short* Ab = (const unsigned short*)Aptr + aBase;
            #pragma unroll
            for (int t = 0; t < 2; t++) {
                int rowb = wave * 32 + t * 16;
                int gm = m0 + rowb + (lane >> 2); if (gm > M - 1) gm = M - 1;
                gload_lds16(Ab + (long)gm * lda + k0 + (lane & 3) * 8,
                            &A_s[rowb * 32]);
            }
        }
        // ---- stage B ----
        #pragma unroll
        for (int t = 0; t < 2; t++) {
            int rowb = wave * 32 + t * 16;
            int gn = n0 + rowb + (lane >> 2); if (gn > N - 1) gn = N - 1;
            gload_lds16(Bp + bBase + (long)gn * ldb + k0 + (lane & 3) * 8,
                        &B_s[rowb * 32]);
        }
        __syncthreads();
        f16x8 a[4], b[4];
        #pragma unroll
        for (int i = 0; i < 4; i++)
            a[i] = *(const f16x8*)&A_s[(wm + i * 16 + l16) * 32 + quad * 8];
        #pragma unroll
        for (int j = 0; j < 4; j++)
            b[j] = *(const f16x8*)&B_s[(wn + j * 16 + l16) * 32 + quad * 8];
        #pragma unroll
        for (int i = 0; i < 4; i++)
            #pragma unroll
            for (int j = 0; j < 4; j++)
                acc[i][j] = __builtin_amdgcn_mfma_f32_16x16x32_f16(
                    a[i], b[j], acc[i][j], 0, 0, 0);
        __syncthreads();
    }

    #pragma unroll
    for (int i = 0; i < 4; i++) {
        #pragma unroll
        for (int j = 0; j < 4; j++) {
            #pragma unroll
            for (int r = 0; r < 4; r++) {
                int gm = m0 + wm + i * 16 + quad * 4 + r;
                int gn = n0 + wn + j * 16 + l16;
                if (gm >= M || gn >= N) continue;
                float v = acc[i][j][r];
                if (EPI == 0) {
                    C[(long)bz * strC + (long)gm * ldc + gn] = v;
                } else if (EPI == 1) {
                    v = tanhf(v + bias[gn]);
                    unsigned short hv = f2h(v);
                    outH[(long)gm * ldc + gn] = hv;
                    int bb = gm >> 9, s = gm & 511;
                    outHT[((long)bb * 256 + gn) * 512 + s] = hv;
                } else if (EPI == 2) {
                    int tok = tokens[(long)bz * 512 + gn];
                    if (tok == 0 || tok == 101 || tok == 102) v -= 1e30f;
                    C[(long)bz * strC + (long)gm * ldc + gn] = v;
                } else if (EPI == 3) {
                    outH[(long)bz * strC + (long)gm * ldc + gn] = f2h(v);
                } else { // EPI 4
                    atomicAdd(C + (long)gm * ldc + gn, v);
                }
            }
        }
    }
}

// ---------------------------------------------------------------------------
// gate_pre: G[j][m][n] = label_enc[m] @ W_j + b_j for j in {i1,f1,o1,u1,i2,o2,u2}
// grid (28, 141): x = j*4+ntile. 64n x 4ks split, unroll-4.
// ---------------------------------------------------------------------------
__global__ __launch_bounds__(256) void gate_pre(
    const float* __restrict__ le,
    const float* W0, const float* W1, const float* W2, const float* W3,
    const float* W4, const float* W5, const float* W6,
    const float* b0, const float* b1, const float* b2, const float* b3,
    const float* b4, const float* b5, const float* b6,
    float* __restrict__ G)
{
    __shared__ float ls[256];
    __shared__ float red[256];
    const int j = blockIdx.x >> 2, x = blockIdx.x & 3, m = blockIdx.y;
    const int tid = threadIdx.x, nl = tid & 63, ks = tid >> 6, n = x * 64 + nl;
    ls[tid] = le[(long)m * 256 + tid];
    __syncthreads();
    const float *W, *bb;
    switch (j) {
        case 0: W = W0; bb = b0; break;  case 1: W = W1; bb = b1; break;
        case 2: W = W2; bb = b2; break;  case 3: W = W3; bb = b3; break;
        case 4: W = W4; bb = b4; break;  case 5: W = W5; bb = b5; break;
        default: W = W6; bb = b6;
    }
    float a0 = 0, a1 = 0, a2 = 0, a3 = 0;
    for (int k = ks; k + 12 < 256; k += 16) {
        long o = (long)k * 256 + n;
        a0 += ls[k] * W[o];        a1 += ls[k + 4] * W[o + 1024];
        a2 += ls[k + 8] * W[o + 2048]; a3 += ls[k + 12] * W[o + 3072];
    }
    red[tid] = a0 + a1 + a2 + a3;
    __syncthreads();
    if (ks == 0)
        G[((long)j * 141 + m) * 256 + n] =
            red[nl] + red[64 + nl] + red[128 + nl] + red[192 + nl] + bb[n];
}

// ---------------------------------------------------------------------------
// pre2: independent two-stage row ops.
// job0 (141r): t = A[m]@label_enc (K=141); tmpP = relu(t@Wp)
// job1 (98r):  t = (w23^T@v2)[m] (K=34);   wv2f = t@wf2_W
// job2 (34r):  t = (w12^T@v1)[m] (K=9);    wv1f = t@wf2_W
// grid (4, 273).
// ---------------------------------------------------------------------------
__global__ __launch_bounds__(256) void pre2(
    const float* __restrict__ A, const float* __restrict__ le,
    const float* __restrict__ w23, const float* __restrict__ w12,
    const float* __restrict__ Wp, const float* __restrict__ wf2_W,
    float* __restrict__ tmpP, float* __restrict__ wv2f, float* __restrict__ wv1f)
{
    __shared__ float cs[141];
    __shared__ float t[256];
    __shared__ float red[256];
    const int x = blockIdx.x, y = blockIdx.y;
    const int tid = threadIdx.x, nl = tid & 63, ks = tid >> 6, n = x * 64 + nl;
    int job, m, K1;
    if (y < 141)      { job = 0; m = y;       K1 = 141; }
    else if (y < 239) { job = 1; m = y - 141; K1 = 34; }
    else              { job = 2; m = y - 239; K1 = 9; }
    if (tid < K1)
        cs[tid] = (job == 0) ? A[(long)m * 141 + tid]
                : (job == 1) ? w23[(long)tid * 98 + m]
                             : w12[(long)tid * 34 + m];
    __syncthreads();
    const float* s1 = (job == 1) ? le + 9 * 256 : le;  // v2 for job1; v1==le rows for job2
    float acc = 0;
    #pragma unroll 4
    for (int k = 0; k < K1; k++) acc += cs[k] * s1[(long)k * 256 + tid];
    t[tid] = acc;
    __syncthreads();
    const float* W = (job == 0) ? Wp : wf2_W;
    float a0 = 0, a1 = 0, a2 = 0, a3 = 0;
    for (int k = ks; k + 12 < 256; k += 16) {
        long o = (long)k * 256 + n;
        a0 += t[k] * W[o];        a1 += t[k + 4] * W[o + 1024];
        a2 += t[k + 8] * W[o + 2048]; a3 += t[k + 12] * W[o + 3072];
    }
    red[tid] = a0 + a1 + a2 + a3;
    __syncthreads();
    if (ks == 0) {
        float tot = red[nl] + red[64 + nl] + red[128 + nl] + red[192 + nl];
        if (job == 0)      tmpP[(long)m * 256 + n] = fmaxf(tot, 0.f);
        else if (job == 1) wv2f[(long)m * 256 + n] = tot;
        else               wv1f[(long)m * 256 + n] = tot;
    }
}

// L1: elementwise gates -> h11,c11 (9r from G1) and h32,c32 (98r from G2). grid(107)
__global__ __launch_bounds__(256) void ew1(
    const float* __restrict__ G, float* __restrict__ h11, float* __restrict__ c11,
    float* __restrict__ h32, float* __restrict__ c32)
{
    int y = blockIdx.x, n = threadIdx.x;
    if (y < 9) {
        int m = y;
        float iv = sigf(G[(0L * 141 + m) * 256 + n]);
        float ov = sigf(G[(2L * 141 + m) * 256 + n]);
        float uv = tanhf(G[(3L * 141 + m) * 256 + n]);
        float cv = iv * uv;
        c11[m * 256 + n] = cv; h11[m * 256 + n] = ov * tanhf(cv);
    } else {
        int r = y - 9, grow = 43 + r;
        float iv = sigf(G[(4L * 141 + grow) * 256 + n]);
        float ov = sigf(G[(5L * 141 + grow) * 256 + n]);
        float uv = tanhf(G[(6L * 141 + grow) * 256 + n]);
        float cv = iv * uv;
        c32[r * 256 + n] = cv; h32[r * 256 + n] = ov * tanhf(cv);
    }
}

// ---------------------------------------------------------------------------
// chain_mm: phase0 grid(4,200): j0 h21t=w12^T@h11(K9), j1 c21p=w12^T@c11(K9),
//   j2 h22t=fre23@h32(K98), j3 fcb=sig(wv2f+wf2_b+h32[m]@uf2_W)*c32 (98r,K256)
// phase1 grid(4,239): j0 h31t=w23^T@h21(K34), j1 c31p=w23^T@c21(K34),
//   j2 h12t=fre12@h22(9r,K34), j3 fc2b=sig(wv1f+wf2_b+h22[m]@uf2_W)*c22 (34r)
// ---------------------------------------------------------------------------
__global__ __launch_bounds__(256) void chain_mm(int phase,
    const float* __restrict__ w12, const float* __restrict__ w23,
    const float* __restrict__ fre23, const float* __restrict__ fre12,
    const float* __restrict__ h11, const float* __restrict__ c11,
    const float* __restrict__ h32,
    const float* __restrict__ h21, const float* __restrict__ c21,
    const float* __restrict__ h22,
    const float* __restrict__ wv2f, const float* __restrict__ wv1f,
    const float* __restrict__ wf2_b, const float* __restrict__ uf2_W,
    const float* __restrict__ c32, const float* __restrict__ c22,
    float* __restrict__ h21t, float* __restrict__ c21p,
    float* __restrict__ h22t, float* __restrict__ fcb,
    float* __restrict__ h31t, float* __restrict__ c31p,
    float* __restrict__ h12t, float* __restrict__ fc2b)
{
    __shared__ float cs[256];
    __shared__ float red[256];
    const int x = blockIdx.x, y = blockIdx.y;
    const int tid = threadIdx.x, nl = tid & 63, ks = tid >> 6, n = x * 64 + nl;
    int job, m;
    if (phase == 0) {
        if (y < 34)       { job = 0; m = y; }
        else if (y < 68)  { job = 1; m = y - 34; }
        else if (y < 102) { job = 2; m = y - 68; }
        else              { job = 3; m = y - 102; }
    } else {
        if (y < 98)       { job = 0; m = y; }
        else if (y < 196) { job = 1; m = y - 98; }
        else if (y < 205) { job = 2; m = y - 196; }
        else              { job = 3; m = y - 205; }
    }
    if (job < 3) {
        int K; const float* src; float* dst;
        if (phase == 0) {
            K = (job == 2) ? 98 : 9;
            src = (job == 0) ? h11 : (job == 1) ? c11 : h32;
            dst = (job == 0) ? h21t : (job == 1) ? c21p : h22t;
            if (tid < K)
                cs[tid] = (job == 2) ? fre23[(long)m * 98 + tid]
                                     : w12[(long)tid * 34 + m];
        } else {
            K = 34;
            src = (job == 0) ? h21 : (job == 1) ? c21 : h22;
            dst = (job == 0) ? h31t : (job == 1) ? c31p : h12t;
            if (tid < K)
                cs[tid] = (job == 2) ? fre12[(long)m * 34 + tid]
                                     : w23[(long)tid * 98 + m];
        }
        __syncthreads();
        float a0 = 0;
        for (int k = ks; k < K; k += 4) a0 += cs[k] * src[(long)k * 256 + n];
        red[tid] = a0;
        __syncthreads();
        if (ks == 0)
            dst[(long)m * 256 + n] = red[nl] + red[64 + nl] + red[128 + nl] + red[192 + nl];
    } else {
        const float* row = (phase == 0) ? h32 + m * 256 : h22 + m * 256;
        const float* pre = (phase == 0) ? wv2f : wv1f;
        const float* cm  = (phase == 0) ? c32 : c22;
        float* dst       = (phase == 0) ? fcb : fc2b;
        cs[tid] = row[tid];
        __syncthreads();
        float a0 = 0, a1 = 0, a2 = 0, a3 = 0;
        for (int k = ks; k + 12 < 256; k += 16) {
            long o = (long)k * 256 + n;
            a0 += cs[k] * uf2_W[o];        a1 += cs[k + 4] * uf2_W[o + 1024];
            a2 += cs[k + 8] * uf2_W[o + 2048]; a3 += cs[k + 12] * uf2_W[o + 3072];
        }
        red[tid] = a0 + a1 + a2 + a3;
        __syncthreads();
        if (ks == 0) {
            float tot = red[nl] + red[64 + nl] + red[128 + nl] + red[192 + nl]
                      + pre[(long)m * 256 + n] + wf2_b[n];
            dst[(long)m * 256 + n] = sigf(tot) * cm[(long)m * 256 + n];
        }
    }
}

// ---------------------------------------------------------------------------
// lstm_fused: phase0 grid(4,68): j0 gates21 (34r, U1 x4, cmod c21p),
//   j1 gates22 (34r, U2 x3 + add22=w23@fcb K98) -> h22,c22
// phase1 grid(4,107): j0 gates31 (98r, U1 x4, cmod c31p) -> h31,
//   j1 gates12 (9r, U2 x3 + add12=w12@fc2b K34) -> h12
// ---------------------------------------------------------------------------
__global__ __launch_bounds__(256) void lstm_fused(int phase,
    const float* __restrict__ G,
    const float* __restrict__ h21t, const float* __restrict__ c21p,
    const float* __restrict__ h22t, const float* __restrict__ fcb,
    const float* __restrict__ h31t, const float* __restrict__ c31p,
    const float* __restrict__ h12t, const float* __restrict__ fc2b,
    const float* __restrict__ w23, const float* __restrict__ w12,
    const float* __restrict__ ui1, const float* __restrict__ uf1,
    const float* __restrict__ uo1, const float* __restrict__ uu1,
    const float* __restrict__ ui2, const float* __restrict__ uo2,
    const float* __restrict__ uu2,
    float* __restrict__ h21, float* __restrict__ c21,
    float* __restrict__ h22, float* __restrict__ c22,
    float* __restrict__ h31, float* __restrict__ h12)
{
    __shared__ float hs[256];
    __shared__ float cs[128];
    __shared__ float red[1024];
    const int x = blockIdx.x, y = blockIdx.y;
    const int tid = threadIdx.x, nl = tid & 63, ks = tid >> 6, n = x * 64 + nl;
    bool modef; int m, grow, Kx = 0;
    const float *hrow, *U0, *U1, *U2, *U3 = nullptr, *Sx = nullptr, *cmod = nullptr;
    float *ho, *co = nullptr;
    if (phase == 0) {
        if (y < 34) { modef = true;  m = y;      grow = 9 + m;  hrow = h21t;
                      U0 = ui1; U1 = uf1; U2 = uo1; U3 = uu1; cmod = c21p; ho = h21; co = c21; }
        else        { modef = false; m = y - 34; grow = 9 + m;  hrow = h22t;
                      U0 = ui2; U1 = uo2; U2 = uu2; Sx = fcb; Kx = 98; ho = h22; co = c22;
                      if (tid < 98) cs[tid] = w23[(long)m * 98 + tid]; }
    } else {
        if (y < 98) { modef = true;  m = y;      grow = 43 + m; hrow = h31t;
                      U0 = ui1; U1 = uf1; U2 = uo1; U3 = uu1; cmod = c31p; ho = h31; co = nullptr; }
        else        { modef = false; m = y - 98; grow = m;      hrow = h12t;
                      U0 = ui2; U1 = uo2; U2 = uu2; Sx = fc2b; Kx = 34; ho = h12; co = nullptr;
                      if (tid < 34) cs[tid] = w12[(long)m * 34 + tid]; }
    }
    hs[tid] = hrow[(long)m * 256 + tid];
    __syncthreads();
    float a0 = 0, a1 = 0, a2 = 0, a3 = 0;
    if (modef) {
        for (int k = ks; k < 256; k += 4) {
            float xv = hs[k]; long o = (long)k * 256 + n;
            a0 += xv * U0[o]; a1 += xv * U1[o]; a2 += xv * U2[o]; a3 += xv * U3[o];
        }
    } else {
        for (int k = ks; k < 256; k += 4) {
            float xv = hs[k]; long o = (long)k * 256 + n;
            a0 += xv * U0[o]; a1 += xv * U1[o]; a2 += xv * U2[o];
        }
        for (int k = ks; k < Kx; k += 4) a3 += cs[k] * Sx[(long)k * 256 + n];
    }
    red[tid] = a0; red[256 + tid] = a1; red[512 + tid] = a2; red[768 + tid] = a3;
    __syncthreads();
    if (ks == 0) {
        float t0 = 0, t1 = 0, t2 = 0, t3 = 0;
        #pragma unroll
        for (int s2 = 0; s2 < 4; s2++) {
            t0 += red[s2 * 64 + nl];       t1 += red[256 + s2 * 64 + nl];
            t2 += red[512 + s2 * 64 + nl]; t3 += red[768 + s2 * 64 + nl];
        }
        if (modef) {
            float ti = t0 + G[(0L * 141 + grow) * 256 + n];
            float tf = t1 + G[(1L * 141 + grow) * 256 + n];
            float to = t2 + G[(2L * 141 + grow) * 256 + n];
            float tu = t3 + G[(3L * 141 + grow) * 256 + n];
            float cv = sigf(ti) * tanhf(tu) + sigf(tf) * cmod[(long)m * 256 + n];
            ho[(long)m * 256 + n] = sigf(to) * tanhf(cv);
            if (co) co[(long)m * 256 + n] = cv;
        } else {
            float ti = t0 + G[(4L * 141 + grow) * 256 + n];
            float to = t1 + G[(5L * 141 + grow) * 256 + n];
            float tu = t2 + G[(6L * 141 + grow) * 256 + n];
            float cv = sigf(ti) * tanhf(tu) + t3;
            ho[(long)m * 256 + n] = sigf(to) * tanhf(cv);
            if (co) co[(long)m * 256 + n] = cv;
        }
    }
}

// L6: le_h[l] = fp16( [h?1(l) | h?2(l) | tmpP(l)] @ mix_W + mix_b ). grid (4,141)
__global__ __launch_bounds__(256) void mix_mm(
    const float* __restrict__ h11, const float* __restrict__ h12,
    const float* __restrict__ h21, const float* __restrict__ h22,
    const float* __restrict__ h31, const float* __restrict__ h32,
    const float* __restrict__ tmpP, const float* __restrict__ mix_W,
    const float* __restrict__ mix_b, unsigned short* __restrict__ le_h)
{
    __shared__ float ls[768];
    __shared__ float red[256];
    const int x = blockIdx.x, l = blockIdx.y;
    const int tid = threadIdx.x, nl = tid & 63, ks = tid >> 6, n = x * 64 + nl;
    const float *pa, *pb; int r;
    if (l < 9)       { pa = h11; pb = h12; r = l; }
    else if (l < 43) { pa = h21; pb = h22; r = l - 9; }
    else             { pa = h31; pb = h32; r = l - 43; }
    for (int j = tid; j < 768; j += 256) {
        float v;
        if (j < 256)      v = pa[r * 256 + j];
        else if (j < 512) v = pb[r * 256 + (j - 256)];
        else              v = tmpP[l * 256 + (j - 512)];
        ls[j] = v;
    }
    __syncthreads();
    float a0 = 0, a1 = 0, a2 = 0, a3 = 0;
    for (int k = ks; k + 12 < 768; k += 16) {
        long o = (long)k * 256 + n;
        a0 += ls[k] * mix_W[o];        a1 += ls[k + 4] * mix_W[o + 1024];
        a2 += ls[k + 8] * mix_W[o + 2048]; a3 += ls[k + 12] * mix_W[o + 3072];
    }
    red[tid] = a0 + a1 + a2 + a3;
    __syncthreads();
    if (ks == 0) {
        float tot = red[nl] + red[64 + nl] + red[128 + nl] + red[192 + nl] + mix_b[n];
        le_h[(long)l * 256 + n] = f2h(tot);
    }
}

// Row softmax over S=512; fp32 in, fp16 out.
__global__ __launch_bounds__(256) void softmax512(
    const float* __restrict__ att, unsigned short* __restrict__ atth)
{
    __shared__ float red[256];
    const float* row = att + (long)blockIdx.x * 512;
    unsigned short* orow = atth + (long)blockIdx.x * 512;
    int t = threadIdx.x;
    float a = row[t], b = row[t + 256];
    red[t] = fmaxf(a, b);
    __syncthreads();
    for (int s = 128; s > 0; s >>= 1) {
        if (t < s) red[t] = fmaxf(red[t], red[t + s]);
        __syncthreads();
    }
    float m = red[0];
    __syncthreads();
    float ea = __expf(a - m), eb = __expf(b - m);
    red[t] = ea + eb;
    __syncthreads();
    for (int s = 128; s > 0; s >>= 1) {
        if (t < s) red[t] += red[t + s];
        __syncthreads();
    }
    float inv = 1.f / red[0];
    orow[t] = f2h(ea * inv);
    orow[t + 256] = f2h(eb * inv);
}

// tt_W (768x256 fp32 [k][n]) -> tt_Wt (256x768 fp16 [n][k])
__global__ __launch_bounds__(256) void transp_conv768(
    const float* __restrict__ src, unsigned short* __restrict__ dst)
{
    int idx = blockIdx.x * 256 + threadIdx.x;
    int n = idx / 768, k = idx - n * 768;
    dst[idx] = f2h(src[(long)k * 256 + n]);
}

// out_W (36096x141 fp32 [k][n]) -> out_Wh (141x36096 fp16 [n][k]). grid (141,141)
__global__ __launch_bounds__(256) void transp_outW(
    const float* __restrict__ src, unsigned short* __restrict__ dst)
{
    int k = blockIdx.x * 256 + threadIdx.x;
    int n = blockIdx.y;
    dst[(long)n * 36096 + k] = f2h(src[(long)k * 141 + n]);
}

__global__ __launch_bounds__(256) void zero_kernel(float* __restrict__ p, int n)
{
    int i = blockIdx.x * 256 + threadIdx.x;
    if (i < n) p[i] = 0.f;
}

__global__ __launch_bounds__(256) void out_final(
    const float* __restrict__ acc, const float* __restrict__ ob,
    float* __restrict__ out, int total)
{
    int i = blockIdx.x * 256 + threadIdx.x;
    if (i < total) {
        float v = acc[i] + ob[i % L];
        out[i] = sigf(v);
    }
}

extern "C" void kernel_launch(void* const* d_in, const int* in_sizes, int n_in,
                              void* d_out, int out_size, void* d_ws, size_t ws_size,
                              hipStream_t stream)
{
    (void)in_sizes; (void)n_in; (void)out_size; (void)ws_size;
    const int*   inputs      = (const int*)d_in[0];
    const float* text_hidden = (const float*)d_in[1];
    const float* label_enc   = (const float*)d_in[2];
    const float* w12   = (const float*)d_in[3];
    const float* w23   = (const float*)d_in[4];
    const float* fre12 = (const float*)d_in[5];
    const float* fre23 = (const float*)d_in[6];
    const float* wi1_W = (const float*)d_in[7],  *wi1_b = (const float*)d_in[8];
    const float* wf1_W = (const float*)d_in[9],  *wf1_b = (const float*)d_in[10];
    const float* wo1_W = (const float*)d_in[11], *wo1_b = (const float*)d_in[12];
    const float* wu1_W = (const float*)d_in[13], *wu1_b = (const float*)d_in[14];
    const float* wi2_W = (const float*)d_in[15], *wi2_b = (const float*)d_in[16];
    const float* wf2_W = (const float*)d_in[17], *wf2_b = (const float*)d_in[18];
    const float* wo2_W = (const float*)d_in[19], *wo2_b = (const float*)d_in[20];
    const float* wu2_W = (const float*)d_in[21], *wu2_b = (const float*)d_in[22];
    const float* ui1_W = (const float*)d_in[23], *uf1_W = (const float*)d_in[24];
    const float* uo1_W = (const float*)d_in[25], *uu1_W = (const float*)d_in[26];
    const float* ui2_W = (const float*)d_in[27], *uf2_W = (const float*)d_in[28];
    const float* uo2_W = (const float*)d_in[29], *uu2_W = (const float*)d_in[30];
    const float* mix_W = (const float*)d_in[31], *mix_b = (const float*)d_in[32];
    const float* tt_W  = (const float*)d_in[33], *tt_b  = (const float*)d_in[34];
    const float* Amat  = (const float*)d_in[35], *Wp    = (const float*)d_in[36];
    const float* out_W = (const float*)d_in[37], *out_b = (const float*)d_in[38];
    float* out = (float*)d_out;

    // ---- workspace (float units, all 16B-aligned chunks) ----
    float* ws = (float*)d_ws;
    float* att     = ws; ws += (long)B * L * S;                                 // fp32
    unsigned short* text_h  = (unsigned short*)ws; ws += (long)B * S * H / 2;   // [b*s][h]
    unsigned short* text_hT = (unsigned short*)ws; ws += (long)B * S * H / 2;   // [b][h][s]
    unsigned short* att_h   = (unsigned short*)ws; ws += (long)B * L * S / 2;
    unsigned short* tt_Wt   = (unsigned short*)ws; ws += 768 * H / 2;
    unsigned short* le_h    = (unsigned short*)ws; ws += L * H / 2 + 4;
    unsigned short* out_Wh  = (unsigned short*)ws; ws += (long)L * 36096 / 2;   // [n][k]
    unsigned short* feat_h  = (unsigned short*)ws; ws += (long)B * L * H / 2;   // [b][l*256+h]
    float* G    = ws; ws += 7 * 141 * 256;
    float* tmpP = ws; ws += L * H;
    float* wv2f = ws; ws += N3 * H;
    float* wv1f = ws; ws += N2 * H;
    float* h11  = ws; ws += N1 * H;  float* c11  = ws; ws += N1 * H;
    float* h21  = ws; ws += N2 * H;  float* c21  = ws; ws += N2 * H;
    float* h21t = ws; ws += N2 * H;  float* c21p = ws; ws += N2 * H;
    float* h31  = ws; ws += N3 * H;  float* h31t = ws; ws += N3 * H;
    float* c31p = ws; ws += N3 * H;
    float* h32  = ws; ws += N3 * H;  float* c32  = ws; ws += N3 * H;
    float* h22  = ws; ws += N2 * H;  float* c22  = ws; ws += N2 * H;
    float* h22t = ws; ws += N2 * H;  float* fcb  = ws; ws += N3 * H;
    float* h12  = ws; ws += N1 * H;  float* h12t = ws; ws += N1 * H;
    float* fc2b = ws; ws += N2 * H;
    float* outacc = ws; ws += B * L + 4;

    // 1. tt_W -> fp16 transposed
    transp_conv768<<<768 * H / 256, 256, 0, stream>>>(tt_W, tt_Wt);
    // 2. text = tanh(text_hidden @ tt_W + b) -> fp16 both layouts
    gemm_mfma<1, true><<<dim3(H / 128, (B * S) / 128, 1), 256, 0, stream>>>(
        text_hidden, 768, 0, tt_Wt, 768, 0, nullptr, H, 0,
        B * S, H, 768, tt_b, nullptr, text_h, text_hT, 0);
    // 3. gate pre-activations G[7][141][256]
    gate_pre<<<dim3(28, 141), 256, 0, stream>>>(label_enc,
        wi1_W, wf1_W, wo1_W, wu1_W, wi2_W, wo2_W, wu2_W,
        wi1_b, wf1_b, wo1_b, wu1_b, wi2_b, wo2_b, wu2_b, G);
    // 4. independent two-stage rows: tmpP, wv2f, wv1f
    pre2<<<dim3(4, 273), 256, 0, stream>>>(Amat, label_enc, w23, w12, Wp, wf2_W,
        tmpP, wv2f, wv1f);
    // 5. out_W -> fp16 transposed (independent)
    transp_outW<<<dim3(141, 141), 256, 0, stream>>>(out_W, out_Wh);
    zero_kernel<<<(B * L + 255) / 256, 256, 0, stream>>>(outacc, B * L);
    // 6-11. label chain
    ew1<<<107, 256, 0, stream>>>(G, h11, c11, h32, c32);
    chain_mm<<<dim3(4, 200), 256, 0, stream>>>(0, w12, w23, fre23, fre12,
        h11, c11, h32, h21, c21, h22, wv2f, wv1f, wf2_b, uf2_W, c32, c22,
        h21t, c21p, h22t, fcb, h31t, c31p, h12t, fc2b);
    lstm_fused<<<dim3(4, 68), 256, 0, stream>>>(0, G,
        h21t, c21p, h22t, fcb, h31t, c31p, h12t, fc2b, w23, w12,
        ui1_W, uf1_W, uo1_W, uu1_W, ui2_W, uo2_W, uu2_W,
        h21, c21, h22, c22, h31, h12);
    chain_mm<<<dim3(4, 239), 256, 0, stream>>>(1, w12, w23, fre23, fre12,
        h11, c11, h32, h21, c21, h22, wv2f, wv1f, wf2_b, uf2_W, c32, c22,
        h21t, c21p, h22t, fcb, h31t, c31p, h12t, fc2b);
    lstm_fused<<<dim3(4, 107), 256, 0, stream>>>(1, G,
        h21t, c21p, h22t, fcb, h31t, c31p, h12t, fc2b, w23, w12,
        ui1_W, uf1_W, uo1_W, uu1_W, ui2_W, uo2_W, uu2_W,
        h21, c21, h22, c22, h31, h12);
    mix_mm<<<dim3(4, 141), 256, 0, stream>>>(h11, h12, h21, h22, h31, h32,
        tmpP, mix_W, mix_b, le_h);
    // 12. logits (+pad mask) fp32
    gemm_mfma<2, false><<<dim3(S / 128, (L + 127) / 128, B), 256, 0, stream>>>(
        le_h, H, 0, text_h, H, (long)S * H, att, S, (long)L * S,
        L, S, H, nullptr, inputs, nullptr, nullptr, 0);
    // 13. softmax -> fp16
    softmax512<<<B * L, 256, 0, stream>>>(att, att_h);
    // 14. feat (fp16 out, layout [b][l*256+h])
    gemm_mfma<3, false><<<dim3(H / 128, (L + 127) / 128, B), 256, 0, stream>>>(
        att_h, S, (long)L * S, text_hT, S, (long)H * S, nullptr, H, (long)L * H,
        L, H, S, nullptr, nullptr, feat_h, nullptr, 0);
    // 15. out-head: K-split MFMA + atomic fp32
    gemm_mfma<4, false><<<dim3(2, 1, 141), 256, 0, stream>>>(
        feat_h, L * H, 0, out_Wh, L * H, 0, outacc, L, 0,
        B, L, L * H, nullptr, nullptr, nullptr, nullptr, 256);
    // 16. sigmoid + bias
    out_final<<<(B * L + 255) / 256, 256, 0, stream>>>(outacc, out_b, out, B * L);
}

// Round 6
// 489.175 us; speedup vs baseline: 3.7697x; 1.0964x over previous
//
#include <hip/hip_runtime.h>
#include <math.h>

// Problem constants
static constexpr int H = 256, L = 141, N1 = 9, N2 = 34, N3 = 98;
static constexpr int B = 64, S = 512;

typedef __attribute__((ext_vector_type(8))) _Float16 f16x8;
typedef __attribute__((ext_vector_type(4))) float f32x4;

__device__ inline unsigned short f2h(float x) {
    _Float16 h = (_Float16)x;
    return __builtin_bit_cast(unsigned short, h);
}
__device__ inline float sigf(float x) { return 1.f / (1.f + __expf(-x)); }

__device__ inline void gload_lds16(const void* g, void* l) {
    __builtin_amdgcn_global_load_lds(
        (const __attribute__((address_space(1))) void*)g,
        (__attribute__((address_space(3))) void*)l, 16, 0, 0);
}

// ---------------------------------------------------------------------------
// MFMA fp16 GEMM. Tile = (32*IM) x 128, BK=32, 16x16x32_f16, 4 waves.
// IM=2: 64-row tiles (more blocks -> occupancy; less pad waste at M=141).
// A: [M][K] k-contig (f16, or fp32 if CONVA). B: [N][K] k-contig f16.
// A rows clamped to M-1, B rows clamped to N-1 (guarded in epilogue).
// EPI 1: tanh(acc+bias[n]) -> outH[m][n] + LDS-tiled transposed outHT
//        [(b*256+n)*512+s] written as 64B/lane full lines. (CONVA text only)
// EPI 2: pad-mask + fp32 C (batched, bz=batch).
// EPI 3: fp16 outH (batched).
// EPI 4: K-split (bz = k-chunk of kChunk) -> fp32 partial slice C[bz][m][n].
// ---------------------------------------------------------------------------
template<int EPI, bool CONVA, int IM>
__global__ __launch_bounds__(256) void gemm_mfma(
    const void* __restrict__ Aptr, int lda, long strA,
    const unsigned short* __restrict__ Bp, int ldb, long strB,
    float* __restrict__ C, int ldc, long strC,
    int M, int N, int K,
    const float* __restrict__ bias,
    const int* __restrict__ tokens,
    unsigned short* __restrict__ outH,
    unsigned short* __restrict__ outHT,
    int kChunk)
{
    __shared__ unsigned short A_s[32 * IM * 32];
    __shared__ unsigned short B_s[128 * 32];
    __shared__ unsigned short T[EPI == 1 ? 128 * 64 : 1];  // [n_local][m_local]
    const int tid  = threadIdx.x;
    const int wave = tid >> 6, lane = tid & 63;
    const int quad = lane >> 4, l16 = lane & 15;
    const int bz = blockIdx.z;
    const int m0 = blockIdx.y * (32 * IM), n0 = blockIdx.x * 128;
    const int wm = (wave & 1) * (16 * IM), wn = (wave >> 1) * 64;

    long aBase, bBase;
    int kBeg, kEnd;
    if (EPI == 4) { aBase = 0; bBase = 0; kBeg = bz * kChunk; kEnd = kBeg + kChunk; }
    else { aBase = (long)bz * strA; bBase = (long)bz * strB; kBeg = 0; kEnd = K; }

    f32x4 acc[IM][4] = {};

    for (int k0 = kBeg; k0 < kEnd; k0 += 32) {
        // ---- stage A ----
        if (CONVA) {
            const float* Af = (const float*)Aptr + aBase;
            #pragma unroll
            for (int it = 0; it < IM; it++) {
                int idx = it * 256 + tid;
                int row = idx >> 3, col4 = idx & 7;
                int gm = m0 + row; if (gm > M - 1) gm = M - 1;
                float4 v = *(const float4*)(Af + (long)gm * lda + k0 + col4 * 4);
                unsigned int p0 = f2h(v.x) | ((unsigned int)f2h(v.y) << 16);
                unsigned int p1 = f2h(v.z) | ((unsigned int)f2h(v.w) << 16);
                *(uint2*)&A_s[row * 32 + col4 * 4] = make_uint2(p0, p1);
            }
        } else {
            const unsigned short* Ab = (const unsigned short*)Aptr + aBase;
            #pragma unroll
            for (int t = 0; t < IM / 2; t++) {
                int rowb = wave * (8 * IM) + t * 16;
                int gm = m0 + rowb + (lane >> 2); if (gm > M - 1) gm = M - 1;
                gload_lds16(Ab + (long)gm * lda + k0 + (lane & 3) * 8,
                            &A_s[rowb * 32]);
            }
        }
        // ---- stage B ----
        #pragma unroll
        for (int t = 0; t < 2; t++) {
            int rowb = wave * 32 + t * 16;
            int gn = n0 + rowb + (lane >> 2); if (gn > N - 1) gn = N - 1;
            gload_lds16(Bp + bBase + (long)gn * ldb + k0 + (lane & 3) * 8,
                        &B_s[rowb * 32]);
        }
        __syncthreads();
        f16x8 a[IM], b[4];
        #pragma unroll
        for (int i = 0; i < IM; i++)
            a[i] = *(const f16x8*)&A_s[(wm + i * 16 + l16) * 32 + quad * 8];
        #pragma unroll
        for (int j = 0; j < 4; j++)
            b[j] = *(const f16x8*)&B_s[(wn + j * 16 + l16) * 32 + quad * 8];
        #pragma unroll
        for (int i = 0; i < IM; i++)
            #pragma unroll
            for (int j = 0; j < 4; j++)
                acc[i][j] = __builtin_amdgcn_mfma_f32_16x16x32_f16(
                    a[i], b[j], acc[i][j], 0, 0, 0);
        __syncthreads();
    }

    #pragma unroll
    for (int i = 0; i < IM; i++) {
        #pragma unroll
        for (int j = 0; j < 4; j++) {
            #pragma unroll
            for (int r = 0; r < 4; r++) {
                int ml = wm + i * 16 + quad * 4 + r;
                int nl = wn + j * 16 + l16;
                int gm = m0 + ml, gn = n0 + nl;
                if (gm >= M || gn >= N) continue;
                float v = acc[i][j][r];
                if (EPI == 1) {
                    v = tanhf(v + bias[gn]);
                    unsigned short hv = f2h(v);
                    outH[(long)gm * ldc + gn] = hv;
                    T[nl * 64 + ml] = hv;
                } else if (EPI == 2) {
                    int tok = tokens[(long)bz * 512 + gn];
                    if (tok == 0 || tok == 101 || tok == 102) v -= 1e30f;
                    C[(long)bz * strC + (long)gm * ldc + gn] = v;
                } else if (EPI == 3) {
                    outH[(long)bz * strC + (long)gm * ldc + gn] = f2h(v);
                } else { // EPI 4: partial K-slice
                    C[(long)bz * strC + (long)gm * ldc + gn] = v;
                }
            }
        }
    }
    if (EPI == 1) {
        // coalesced transposed write: 128 h-rows x 64 s each (128B/lane = 2 lines)
        __syncthreads();
        int bb = m0 >> 9, s0 = m0 & 511;
        int rr = tid >> 1, half = tid & 1;
        const uint4* srcp = (const uint4*)&T[rr * 64 + half * 32];
        uint4* dstp = (uint4*)&outHT[((long)bb * 256 + n0 + rr) * 512 + s0 + half * 32];
        dstp[0] = srcp[0]; dstp[1] = srcp[1]; dstp[2] = srcp[2]; dstp[3] = srcp[3];
    }
}

// ---------------------------------------------------------------------------
// LDS-tiled transpose+convert: src fp32 [R][C] -> dst fp16 [C][R].
// grid (R/64, ceil(C/64)). Both global passes fully coalesced.
// ---------------------------------------------------------------------------
__global__ __launch_bounds__(256) void transp_t64(
    const float* __restrict__ src, unsigned short* __restrict__ dst,
    int R, int C)
{
    __shared__ unsigned short T[64 * 65];
    const int tid = threadIdx.x;
    const int r0 = blockIdx.x * 64, c0 = blockIdx.y * 64;
    #pragma unroll
    for (int p = 0; p < 16; p++) {
        int lin = p * 256 + tid;
        int r = lin >> 6, c = lin & 63;
        int gc = c0 + c;
        float v = (gc < C) ? src[(long)(r0 + r) * C + gc] : 0.f;
        T[c * 65 + r] = f2h(v);
    }
    __syncthreads();
    #pragma unroll
    for (int p = 0; p < 16; p++) {
        int lin = p * 256 + tid;
        int c = lin >> 6, r = lin & 63;
        if (c0 + c < C)
            dst[(long)(c0 + c) * R + r0 + r] = T[c * 65 + r];
    }
}

// ---------------------------------------------------------------------------
// gate_pre: G[j][m][n] = label_enc[m] @ W_j + b_j, j in {i1,f1,o1,u1,i2,o2,u2}
// grid (28, 141). 64n x 4ks split, unroll-4.
// ---------------------------------------------------------------------------
__global__ __launch_bounds__(256) void gate_pre(
    const float* __restrict__ le,
    const float* W0, const float* W1, const float* W2, const float* W3,
    const float* W4, const float* W5, const float* W6,
    const float* b0, const float* b1, const float* b2, const float* b3,
    const float* b4, const float* b5, const float* b6,
    float* __restrict__ G)
{
    __shared__ float ls[256];
    __shared__ float red[256];
    const int j = blockIdx.x >> 2, x = blockIdx.x & 3, m = blockIdx.y;
    const int tid = threadIdx.x, nl = tid & 63, ks = tid >> 6, n = x * 64 + nl;
    ls[tid] = le[(long)m * 256 + tid];
    __syncthreads();
    const float *W, *bb;
    switch (j) {
        case 0: W = W0; bb = b0; break;  case 1: W = W1; bb = b1; break;
        case 2: W = W2; bb = b2; break;  case 3: W = W3; bb = b3; break;
        case 4: W = W4; bb = b4; break;  case 5: W = W5; bb = b5; break;
        default: W = W6; bb = b6;
    }
    float a0 = 0, a1 = 0, a2 = 0, a3 = 0;
    for (int k = ks; k + 12 < 256; k += 16) {
        long o = (long)k * 256 + n;
        a0 += ls[k] * W[o];        a1 += ls[k + 4] * W[o + 1024];
        a2 += ls[k + 8] * W[o + 2048]; a3 += ls[k + 12] * W[o + 3072];
    }
    red[tid] = a0 + a1 + a2 + a3;
    __syncthreads();
    if (ks == 0)
        G[((long)j * 141 + m) * 256 + n] =
            red[nl] + red[64 + nl] + red[128 + nl] + red[192 + nl] + bb[n];
}

// ---------------------------------------------------------------------------
// pre2: independent two-stage row ops (see round-5 comments). grid (4, 273).
// ---------------------------------------------------------------------------
__global__ __launch_bounds__(256) void pre2(
    const float* __restrict__ A, const float* __restrict__ le,
    const float* __restrict__ w23, const float* __restrict__ w12,
    const float* __restrict__ Wp, const float* __restrict__ wf2_W,
    float* __restrict__ tmpP, float* __restrict__ wv2f, float* __restrict__ wv1f)
{
    __shared__ float cs[141];
    __shared__ float t[256];
    __shared__ float red[256];
    const int x = blockIdx.x, y = blockIdx.y;
    const int tid = threadIdx.x, nl = tid & 63, ks = tid >> 6, n = x * 64 + nl;
    int job, m, K1;
    if (y < 141)      { job = 0; m = y;       K1 = 141; }
    else if (y < 239) { job = 1; m = y - 141; K1 = 34; }
    else              { job = 2; m = y - 239; K1 = 9; }
    if (tid < K1)
        cs[tid] = (job == 0) ? A[(long)m * 141 + tid]
                : (job == 1) ? w23[(long)tid * 98 + m]
                             : w12[(long)tid * 34 + m];
    __syncthreads();
    const float* s1 = (job == 1) ? le + 9 * 256 : le;
    float acc = 0;
    #pragma unroll 4
    for (int k = 0; k < K1; k++) acc += cs[k] * s1[(long)k * 256 + tid];
    t[tid] = acc;
    __syncthreads();
    const float* W = (job == 0) ? Wp : wf2_W;
    float a0 = 0, a1 = 0, a2 = 0, a3 = 0;
    for (int k = ks; k + 12 < 256; k += 16) {
        long o = (long)k * 256 + n;
        a0 += t[k] * W[o];        a1 += t[k + 4] * W[o + 1024];
        a2 += t[k + 8] * W[o + 2048]; a3 += t[k + 12] * W[o + 3072];
    }
    red[tid] = a0 + a1 + a2 + a3;
    __syncthreads();
    if (ks == 0) {
        float tot = red[nl] + red[64 + nl] + red[128 + nl] + red[192 + nl];
        if (job == 0)      tmpP[(long)m * 256 + n] = fmaxf(tot, 0.f);
        else if (job == 1) wv2f[(long)m * 256 + n] = tot;
        else               wv1f[(long)m * 256 + n] = tot;
    }
}

// L1: elementwise gates -> h11,c11 (9r) and h32,c32 (98r). grid(107)
__global__ __launch_bounds__(256) void ew1(
    const float* __restrict__ G, float* __restrict__ h11, float* __restrict__ c11,
    float* __restrict__ h32, float* __restrict__ c32)
{
    int y = blockIdx.x, n = threadIdx.x;
    if (y < 9) {
        int m = y;
        float iv = sigf(G[(0L * 141 + m) * 256 + n]);
        float ov = sigf(G[(2L * 141 + m) * 256 + n]);
        float uv = tanhf(G[(3L * 141 + m) * 256 + n]);
        float cv = iv * uv;
        c11[m * 256 + n] = cv; h11[m * 256 + n] = ov * tanhf(cv);
    } else {
        int r = y - 9, grow = 43 + r;
        float iv = sigf(G[(4L * 141 + grow) * 256 + n]);
        float ov = sigf(G[(5L * 141 + grow) * 256 + n]);
        float uv = tanhf(G[(6L * 141 + grow) * 256 + n]);
        float cv = iv * uv;
        c32[r * 256 + n] = cv; h32[r * 256 + n] = ov * tanhf(cv);
    }
}

// chain_mm: fused sparse/row matmuls (see round-5 comments).
__global__ __launch_bounds__(256) void chain_mm(int phase,
    const float* __restrict__ w12, const float* __restrict__ w23,
    const float* __restrict__ fre23, const float* __restrict__ fre12,
    const float* __restrict__ h11, const float* __restrict__ c11,
    const float* __restrict__ h32,
    const float* __restrict__ h21, const float* __restrict__ c21,
    const float* __restrict__ h22,
    const float* __restrict__ wv2f, const float* __restrict__ wv1f,
    const float* __restrict__ wf2_b, const float* __restrict__ uf2_W,
    const float* __restrict__ c32, const float* __restrict__ c22,
    float* __restrict__ h21t, float* __restrict__ c21p,
    float* __restrict__ h22t, float* __restrict__ fcb,
    float* __restrict__ h31t, float* __restrict__ c31p,
    float* __restrict__ h12t, float* __restrict__ fc2b)
{
    __shared__ float cs[256];
    __shared__ float red[256];
    const int x = blockIdx.x, y = blockIdx.y;
    const int tid = threadIdx.x, nl = tid & 63, ks = tid >> 6, n = x * 64 + nl;
    int job, m;
    if (phase == 0) {
        if (y < 34)       { job = 0; m = y; }
        else if (y < 68)  { job = 1; m = y - 34; }
        else if (y < 102) { job = 2; m = y - 68; }
        else              { job = 3; m = y - 102; }
    } else {
        if (y < 98)       { job = 0; m = y; }
        else if (y < 196) { job = 1; m = y - 98; }
        else if (y < 205) { job = 2; m = y - 196; }
        else              { job = 3; m = y - 205; }
    }
    if (job < 3) {
        int K; const float* src; float* dst;
        if (phase == 0) {
            K = (job == 2) ? 98 : 9;
            src = (job == 0) ? h11 : (job == 1) ? c11 : h32;
            dst = (job == 0) ? h21t : (job == 1) ? c21p : h22t;
            if (tid < K)
                cs[tid] = (job == 2) ? fre23[(long)m * 98 + tid]
                                     : w12[(long)tid * 34 + m];
        } else {
            K = 34;
            src = (job == 0) ? h21 : (job == 1) ? c21 : h22;
            dst = (job == 0) ? h31t : (job == 1) ? c31p : h12t;
            if (tid < K)
                cs[tid] = (job == 2) ? fre12[(long)m * 34 + tid]
                                     : w23[(long)tid * 98 + m];
        }
        __syncthreads();
        float a0 = 0;
        for (int k = ks; k < K; k += 4) a0 += cs[k] * src[(long)k * 256 + n];
        red[tid] = a0;
        __syncthreads();
        if (ks == 0)
            dst[(long)m * 256 + n] = red[nl] + red[64 + nl] + red[128 + nl] + red[192 + nl];
    } else {
        const float* row = (phase == 0) ? h32 + m * 256 : h22 + m * 256;
        const float* pre = (phase == 0) ? wv2f : wv1f;
        const float* cm  = (phase == 0) ? c32 : c22;
        float* dst       = (phase == 0) ? fcb : fc2b;
        cs[tid] = row[tid];
        __syncthreads();
        float a0 = 0, a1 = 0, a2 = 0, a3 = 0;
        for (int k = ks; k + 12 < 256; k += 16) {
            long o = (long)k * 256 + n;
            a0 += cs[k] * uf2_W[o];        a1 += cs[k + 4] * uf2_W[o + 1024];
            a2 += cs[k + 8] * uf2_W[o + 2048]; a3 += cs[k + 12] * uf2_W[o + 3072];
        }
        red[tid] = a0 + a1 + a2 + a3;
        __syncthreads();
        if (ks == 0) {
            float tot = red[nl] + red[64 + nl] + red[128 + nl] + red[192 + nl]
                      + pre[(long)m * 256 + n] + wf2_b[n];
            dst[(long)m * 256 + n] = sigf(tot) * cm[(long)m * 256 + n];
        }
    }
}

// lstm_fused: fused gate matmuls + elementwise (see round-5 comments).
__global__ __launch_bounds__(256) void lstm_fused(int phase,
    const float* __restrict__ G,
    const float* __restrict__ h21t, const float* __restrict__ c21p,
    const float* __restrict__ h22t, const float* __restrict__ fcb,
    const float* __restrict__ h31t, const float* __restrict__ c31p,
    const float* __restrict__ h12t, const float* __restrict__ fc2b,
    const float* __restrict__ w23, const float* __restrict__ w12,
    const float* __restrict__ ui1, const float* __restrict__ uf1,
    const float* __restrict__ uo1, const float* __restrict__ uu1,
    const float* __restrict__ ui2, const float* __restrict__ uo2,
    const float* __restrict__ uu2,
    float* __restrict__ h21, float* __restrict__ c21,
    float* __restrict__ h22, float* __restrict__ c22,
    float* __restrict__ h31, float* __restrict__ h12)
{
    __shared__ float hs[256];
    __shared__ float cs[128];
    __shared__ float red[1024];
    const int x = blockIdx.x, y = blockIdx.y;
    const int tid = threadIdx.x, nl = tid & 63, ks = tid >> 6, n = x * 64 + nl;
    bool modef; int m, grow, Kx = 0;
    const float *hrow, *U0, *U1, *U2, *U3 = nullptr, *Sx = nullptr, *cmod = nullptr;
    float *ho, *co = nullptr;
    if (phase == 0) {
        if (y < 34) { modef = true;  m = y;      grow = 9 + m;  hrow = h21t;
                      U0 = ui1; U1 = uf1; U2 = uo1; U3 = uu1; cmod = c21p; ho = h21; co = c21; }
        else        { modef = false; m = y - 34; grow = 9 + m;  hrow = h22t;
                      U0 = ui2; U1 = uo2; U2 = uu2; Sx = fcb; Kx = 98; ho = h22; co = c22;
                      if (tid < 98) cs[tid] = w23[(long)m * 98 + tid]; }
    } else {
        if (y < 98) { modef = true;  m = y;      grow = 43 + m; hrow = h31t;
                      U0 = ui1; U1 = uf1; U2 = uo1; U3 = uu1; cmod = c31p; ho = h31; co = nullptr; }
        else        { modef = false; m = y - 98; grow = m;      hrow = h12t;
                      U0 = ui2; U1 = uo2; U2 = uu2; Sx = fc2b; Kx = 34; ho = h12; co = nullptr;
                      if (tid < 34) cs[tid] = w12[(long)m * 34 + tid]; }
    }
    hs[tid] = hrow[(long)m * 256 + tid];
    __syncthreads();
    float a0 = 0, a1 = 0, a2 = 0, a3 = 0;
    if (modef) {
        for (int k = ks; k < 256; k += 4) {
            float xv = hs[k]; long o = (long)k * 256 + n;
            a0 += xv * U0[o]; a1 += xv * U1[o]; a2 += xv * U2[o]; a3 += xv * U3[o];
        }
    } else {
        for (int k = ks; k < 256; k += 4) {
            float xv = hs[k]; long o = (long)k * 256 + n;
            a0 += xv * U0[o]; a1 += xv * U1[o]; a2 += xv * U2[o];
        }
        for (int k = ks; k < Kx; k += 4) a3 += cs[k] * Sx[(long)k * 256 + n];
    }
    red[tid] = a0; red[256 + tid] = a1; red[512 + tid] = a2; red[768 + tid] = a3;
    __syncthreads();
    if (ks == 0) {
        float t0 = 0, t1 = 0, t2 = 0, t3 = 0;
        #pragma unroll
        for (int s2 = 0; s2 < 4; s2++) {
            t0 += red[s2 * 64 + nl];       t1 += red[256 + s2 * 64 + nl];
            t2 += red[512 + s2 * 64 + nl]; t3 += red[768 + s2 * 64 + nl];
        }
        if (modef) {
            float ti = t0 + G[(0L * 141 + grow) * 256 + n];
            float tf = t1 + G[(1L * 141 + grow) * 256 + n];
            float to = t2 + G[(2L * 141 + grow) * 256 + n];
            float tu = t3 + G[(3L * 141 + grow) * 256 + n];
            float cv = sigf(ti) * tanhf(tu) + sigf(tf) * cmod[(long)m * 256 + n];
            ho[(long)m * 256 + n] = sigf(to) * tanhf(cv);
            if (co) co[(long)m * 256 + n] = cv;
        } else {
            float ti = t0 + G[(4L * 141 + grow) * 256 + n];
            float to = t1 + G[(5L * 141 + grow) * 256 + n];
            float tu = t2 + G[(6L * 141 + grow) * 256 + n];
            float cv = sigf(ti) * tanhf(tu) + t3;
            ho[(long)m * 256 + n] = sigf(to) * tanhf(cv);
            if (co) co[(long)m * 256 + n] = cv;
        }
    }
}

// le_h[l] = fp16( [h?1(l) | h?2(l) | tmpP(l)] @ mix_W + mix_b ). grid (4,141)
__global__ __launch_bounds__(256) void mix_mm(
    const float* __restrict__ h11, const float* __restrict__ h12,
    const float* __restrict__ h21, const float* __restrict__ h22,
    const float* __restrict__ h31, const float* __restrict__ h32,
    const float* __restrict__ tmpP, const float* __restrict__ mix_W,
    const float* __restrict__ mix_b, unsigned short* __restrict__ le_h)
{
    __shared__ float ls[768];
    __shared__ float red[256];
    const int x = blockIdx.x, l = blockIdx.y;
    const int tid = threadIdx.x, nl = tid & 63, ks = tid >> 6, n = x * 64 + nl;
    const float *pa, *pb; int r;
    if (l < 9)       { pa = h11; pb = h12; r = l; }
    else if (l < 43) { pa = h21; pb = h22; r = l - 9; }
    else             { pa = h31; pb = h32; r = l - 43; }
    for (int j = tid; j < 768; j += 256) {
        float v;
        if (j < 256)      v = pa[r * 256 + j];
        else if (j < 512) v = pb[r * 256 + (j - 256)];
        else              v = tmpP[l * 256 + (j - 512)];
        ls[j] = v;
    }
    __syncthreads();
    float a0 = 0, a1 = 0, a2 = 0, a3 = 0;
    for (int k = ks; k + 12 < 768; k += 16) {
        long o = (long)k * 256 + n;
        a0 += ls[k] * mix_W[o];        a1 += ls[k + 4] * mix_W[o + 1024];
        a2 += ls[k + 8] * mix_W[o + 2048]; a3 += ls[k + 12] * mix_W[o + 3072];
    }
    red[tid] = a0 + a1 + a2 + a3;
    __syncthreads();
    if (ks == 0) {
        float tot = red[nl] + red[64 + nl] + red[128 + nl] + red[192 + nl] + mix_b[n];
        le_h[(long)l * 256 + n] = f2h(tot);
    }
}

// Row softmax over S=512; fp32 in, fp16 out.
__global__ __launch_bounds__(256) void softmax512(
    const float* __restrict__ att, unsigned short* __restrict__ atth)
{
    __shared__ float red[256];
    const float* row = att + (long)blockIdx.x * 512;
    unsigned short* orow = atth + (long)blockIdx.x * 512;
    int t = threadIdx.x;
    float a = row[t], b = row[t + 256];
    red[t] = fmaxf(a, b);
    __syncthreads();
    for (int s = 128; s > 0; s >>= 1) {
        if (t < s) red[t] = fmaxf(red[t], red[t + s]);
        __syncthreads();
    }
    float m = red[0];
    __syncthreads();
    float ea = __expf(a - m), eb = __expf(b - m);
    red[t] = ea + eb;
    __syncthreads();
    for (int s = 128; s > 0; s >>= 1) {
        if (t < s) red[t] += red[t + s];
        __syncthreads();
    }
    float inv = 1.f / red[0];
    orow[t] = f2h(ea * inv);
    orow[t + 256] = f2h(eb * inv);
}

// out = sigmoid(bias + sum of nz partial K-slices)
__global__ __launch_bounds__(256) void out_final(
    const float* __restrict__ acc, const float* __restrict__ ob,
    float* __restrict__ out, int total, int nz)
{
    int i = blockIdx.x * 256 + threadIdx.x;
    if (i >= total) return;
    float v = ob[i % L];
    #pragma unroll 4
    for (int z = 0; z < nz; z++) v += acc[(long)z * total + i];
    out[i] = sigf(v);
}

extern "C" void kernel_launch(void* const* d_in, const int* in_sizes, int n_in,
                              void* d_out, int out_size, void* d_ws, size_t ws_size,
                              hipStream_t stream)
{
    (void)in_sizes; (void)n_in; (void)out_size; (void)ws_size;
    const int*   inputs      = (const int*)d_in[0];
    const float* text_hidden = (const float*)d_in[1];
    const float* label_enc   = (const float*)d_in[2];
    const float* w12   = (const float*)d_in[3];
    const float* w23   = (const float*)d_in[4];
    const float* fre12 = (const float*)d_in[5];
    const float* fre23 = (const float*)d_in[6];
    const float* wi1_W = (const float*)d_in[7],  *wi1_b = (const float*)d_in[8];
    const float* wf1_W = (const float*)d_in[9],  *wf1_b = (const float*)d_in[10];
    const float* wo1_W = (const float*)d_in[11], *wo1_b = (const float*)d_in[12];
    const float* wu1_W = (const float*)d_in[13], *wu1_b = (const float*)d_in[14];
    const float* wi2_W = (const float*)d_in[15], *wi2_b = (const float*)d_in[16];
    const float* wf2_W = (const float*)d_in[17], *wf2_b = (const float*)d_in[18];
    const float* wo2_W = (const float*)d_in[19], *wo2_b = (const float*)d_in[20];
    const float* wu2_W = (const float*)d_in[21], *wu2_b = (const float*)d_in[22];
    const float* ui1_W = (const float*)d_in[23], *uf1_W = (const float*)d_in[24];
    const float* uo1_W = (const float*)d_in[25], *uu1_W = (const float*)d_in[26];
    const float* ui2_W = (const float*)d_in[27], *uf2_W = (const float*)d_in[28];
    const float* uo2_W = (const float*)d_in[29], *uu2_W = (const float*)d_in[30];
    const float* mix_W = (const float*)d_in[31], *mix_b = (const float*)d_in[32];
    const float* tt_W  = (const float*)d_in[33], *tt_b  = (const float*)d_in[34];
    const float* Amat  = (const float*)d_in[35], *Wp    = (const float*)d_in[36];
    const float* out_W = (const float*)d_in[37], *out_b = (const float*)d_in[38];
    float* out = (float*)d_out;

    // ---- workspace (float units, 16B-aligned chunks) ----
    float* ws = (float*)d_ws;
    float* att     = ws; ws += (long)B * L * S;                                 // fp32
    unsigned short* text_h  = (unsigned short*)ws; ws += (long)B * S * H / 2;   // [b*s][h]
    unsigned short* text_hT = (unsigned short*)ws; ws += (long)B * S * H / 2;   // [b][h][s]
    unsigned short* att_h   = (unsigned short*)ws; ws += (long)B * L * S / 2;
    unsigned short* tt_Wt   = (unsigned short*)ws; ws += 768 * H / 2;
    unsigned short* le_h    = (unsigned short*)ws; ws += L * H / 2 + 4;
    unsigned short* out_Wh  = (unsigned short*)ws; ws += (long)L * 36096 / 2;   // [n][k]
    unsigned short* feat_h  = (unsigned short*)ws; ws += (long)B * L * H / 2;   // [b][l*256+h]
    float* outacc = ws; ws += (long)B * L * 141;                                // partial K-slices
    float* G    = ws; ws += 7 * 141 * 256;
    float* tmpP = ws; ws += L * H;
    float* wv2f = ws; ws += N3 * H;
    float* wv1f = ws; ws += N2 * H;
    float* h11  = ws; ws += N1 * H;  float* c11  = ws; ws += N1 * H;
    float* h21  = ws; ws += N2 * H;  float* c21  = ws; ws += N2 * H;
    float* h21t = ws; ws += N2 * H;  float* c21p = ws; ws += N2 * H;
    float* h31  = ws; ws += N3 * H;  float* h31t = ws; ws += N3 * H;
    float* c31p = ws; ws += N3 * H;
    float* h32  = ws; ws += N3 * H;  float* c32  = ws; ws += N3 * H;
    float* h22  = ws; ws += N2 * H;  float* c22  = ws; ws += N2 * H;
    float* h22t = ws; ws += N2 * H;  float* fcb  = ws; ws += N3 * H;
    float* h12  = ws; ws += N1 * H;  float* h12t = ws; ws += N1 * H;
    float* fc2b = ws; ws += N2 * H;

    // 1. tt_W (768x256) -> fp16 [256][768]
    transp_t64<<<dim3(768 / 64, 256 / 64), 256, 0, stream>>>(tt_W, tt_Wt, 768, 256);
    // 2. text = tanh(text_hidden @ tt_W + b) -> fp16 both layouts (64-row tiles)
    gemm_mfma<1, true, 2><<<dim3(H / 128, (B * S) / 64, 1), 256, 0, stream>>>(
        text_hidden, 768, 0, tt_Wt, 768, 0, nullptr, H, 0,
        B * S, H, 768, tt_b, nullptr, text_h, text_hT, 0);
    // 3. gate pre-activations G[7][141][256]
    gate_pre<<<dim3(28, 141), 256, 0, stream>>>(label_enc,
        wi1_W, wf1_W, wo1_W, wu1_W, wi2_W, wo2_W, wu2_W,
        wi1_b, wf1_b, wo1_b, wu1_b, wi2_b, wo2_b, wu2_b, G);
    // 4. independent two-stage rows: tmpP, wv2f, wv1f
    pre2<<<dim3(4, 273), 256, 0, stream>>>(Amat, label_enc, w23, w12, Wp, wf2_W,
        tmpP, wv2f, wv1f);
    // 5. out_W (36096x141) -> fp16 [141][36096] (tiled, coalesced both sides)
    transp_t64<<<dim3(36096 / 64, 3), 256, 0, stream>>>(out_W, out_Wh, 36096, 141);
    // 6-11. label chain
    ew1<<<107, 256, 0, stream>>>(G, h11, c11, h32, c32);
    chain_mm<<<dim3(4, 200), 256, 0, stream>>>(0, w12, w23, fre23, fre12,
        h11, c11, h32, h21, c21, h22, wv2f, wv1f, wf2_b, uf2_W, c32, c22,
        h21t, c21p, h22t, fcb, h31t, c31p, h12t, fc2b);
    lstm_fused<<<dim3(4, 68), 256, 0, stream>>>(0, G,
        h21t, c21p, h22t, fcb, h31t, c31p, h12t, fc2b, w23, w12,
        ui1_W, uf1_W, uo1_W, uu1_W, ui2_W, uo2_W, uu2_W,
        h21, c21, h22, c22, h31, h12);
    chain_mm<<<dim3(4, 239), 256, 0, stream>>>(1, w12, w23, fre23, fre12,
        h11, c11, h32, h21, c21, h22, wv2f, wv1f, wf2_b, uf2_W, c32, c22,
        h21t, c21p, h22t, fcb, h31t, c31p, h12t, fc2b);
    lstm_fused<<<dim3(4, 107), 256, 0, stream>>>(1, G,
        h21t, c21p, h22t, fcb, h31t, c31p, h12t, fc2b, w23, w12,
        ui1_W, uf1_W, uo1_W, uu1_W, ui2_W, uo2_W, uu2_W,
        h21, c21, h22, c22, h31, h12);
    mix_mm<<<dim3(4, 141), 256, 0, stream>>>(h11, h12, h21, h22, h31, h32,
        tmpP, mix_W, mix_b, le_h);
    // 12. logits (+pad mask) fp32, 64-row m-tiles (3 tiles for M=141)
    gemm_mfma<2, false, 2><<<dim3(S / 128, (L + 63) / 64, B), 256, 0, stream>>>(
        le_h, H, 0, text_h, H, (long)S * H, att, S, (long)L * S,
        L, S, H, nullptr, inputs, nullptr, nullptr, 0);
    // 13. softmax -> fp16
    softmax512<<<B * L, 256, 0, stream>>>(att, att_h);
    // 14. feat (fp16 out, [b][l*256+h])
    gemm_mfma<3, false, 2><<<dim3(H / 128, (L + 63) / 64, B), 256, 0, stream>>>(
        att_h, S, (long)L * S, text_hT, S, (long)H * S, nullptr, H, (long)L * H,
        L, H, S, nullptr, nullptr, feat_h, nullptr, 0);
    // 15. out-head: K-split MFMA -> 141 partial slices (no atomics)
    gemm_mfma<4, false, 2><<<dim3(2, 1, 141), 256, 0, stream>>>(
        feat_h, L * H, 0, out_Wh, L * H, 0, outacc, L, (long)B * L,
        B, L, L * H, nullptr, nullptr, nullptr, nullptr, 256);
    // 16. reduce + sigmoid + bias
    out_final<<<(B * L + 255) / 256, 256, 0, stream>>>(outacc, out_b, out, B * L, 141);
}